// Round 3
// baseline (500.841 us; speedup 1.0000x reference)
//
#include <hip/hip_runtime.h>
#include <hip/hip_bf16.h>

// Problem constants: B=2, T=4096, E=512, H=8, D=64
#define T_SEQ 4096
#define EMB   512
#define NH    8
#define HD    64
#define BATCH 2
#define M_ROWS (BATCH * T_SEQ)   // 8192
#define NCHUNK 64                // T / CS
#define CS     64                // chunk size
#define BHEADS (BATCH * NH)      // 16

using bf16 = __hip_bfloat16;

__device__ __forceinline__ void bf2f(unsigned u, float& lo, float& hi) {
    lo = __uint_as_float((u & 0xffffu) << 16);
    hi = __uint_as_float(u & 0xffff0000u);
}

// --- dtype-polymorphic load/store helpers (overload on pointer type) -------
__device__ __forceinline__ float load_elem(const bf16* p, size_t i) {
    return __bfloat162float(p[i]);
}
__device__ __forceinline__ float load_elem(const float* p, size_t i) {
    return p[i];
}
// load 8 consecutive elements starting at 16B(bf16)/32B(fp32)-aligned offset
__device__ __forceinline__ void load8(const bf16* p, size_t off, float* f) {
    uint4 u = *reinterpret_cast<const uint4*>(p + off);
    bf2f(u.x, f[0], f[1]); bf2f(u.y, f[2], f[3]);
    bf2f(u.z, f[4], f[5]); bf2f(u.w, f[6], f[7]);
}
__device__ __forceinline__ void load8(const float* p, size_t off, float* f) {
    float4 a = *reinterpret_cast<const float4*>(p + off);
    float4 b = *reinterpret_cast<const float4*>(p + off + 4);
    f[0] = a.x; f[1] = a.y; f[2] = a.z; f[3] = a.w;
    f[4] = b.x; f[5] = b.y; f[6] = b.z; f[7] = b.w;
}
__device__ __forceinline__ void store_elem(bf16* p, size_t i, float v) {
    p[i] = __float2bfloat16(v);
}
__device__ __forceinline__ void store_elem(float* p, size_t i, float v) {
    p[i] = v;
}
template <typename T> struct ModeOf { static constexpr int v = 0; };  // bf16
template <> struct ModeOf<float>    { static constexpr int v = 1; };  // fp32

// ---------------------------------------------------------------------------
// Kernel 0: dtype detector.  If x is really fp32, its low 16-bit halves
// viewed as bf16 have uniform-random exponent bits -> some are huge/NaN.
// Real bf16 N(0,1) data never exceeds ~6.  Writes 0 (bf16) / 1 (fp32).
// ---------------------------------------------------------------------------
__global__ void detect_dtype(const unsigned short* __restrict__ xraw,
                             int* __restrict__ flag)
{
    const int lane = threadIdx.x;   // 64 threads
    bool bad = false;
    for (int i = 0; i < 64; ++i) {
        const unsigned u = xraw[(size_t)(lane + i * 64) * 2];  // even halves
        const float f = __uint_as_float(u << 16);
        if (!(fabsf(f) <= 1e9f)) bad = true;   // catches NaN/inf/huge
    }
    const unsigned long long m = __ballot(bad);
    if (lane == 0) *flag = (m != 0ull) ? 1 : 0;
}

// ---------------------------------------------------------------------------
// Kernel 1: fused QKV projection.  y = x @ W^T + b, feature map elu+1 on Q,K.
// Output layout: (B, H, T, D) bf16.  Templated on input dtype; self-selects
// via the detector flag.  64x64 tile, 256 threads, 4x4 per thread.
// ---------------------------------------------------------------------------
template <typename T>
__global__ __launch_bounds__(256) void qkv_gemm(
    const int* __restrict__ flag,
    const T* __restrict__ x,
    const T* __restrict__ Wq, const T* __restrict__ bq,
    const T* __restrict__ Wk, const T* __restrict__ bk,
    const T* __restrict__ Wv, const T* __restrict__ bv,
    bf16* __restrict__ Qf, bf16* __restrict__ Kf, bf16* __restrict__ Vf)
{
    if (*flag != ModeOf<T>::v) return;

    const int which = blockIdx.z;
    const T* W    = (which == 0) ? Wq : ((which == 1) ? Wk : Wv);
    const T* bias = (which == 0) ? bq : ((which == 1) ? bk : bv);
    bf16* outp    = (which == 0) ? Qf : ((which == 1) ? Kf : Vf);

    __shared__ float As[64][33];   // +1 pad breaks bank conflict
    __shared__ float Bs[64][33];

    const int tid = threadIdx.x;
    const int tx = tid & 15, ty = tid >> 4;
    const int rowbase = blockIdx.y * 64;
    const int colbase = blockIdx.x * 64;
    const int lrow = tid >> 2;         // 0..63
    const int lk   = (tid & 3) << 3;   // 0,8,16,24

    float acc[4][4] = {};

    for (int kt = 0; kt < EMB; kt += 32) {
        float f[8];
        load8(x, (size_t)(rowbase + lrow) * EMB + kt + lk, f);
        #pragma unroll
        for (int i = 0; i < 8; ++i) As[lrow][lk + i] = f[i];
        load8(W, (size_t)(colbase + lrow) * EMB + kt + lk, f);
        #pragma unroll
        for (int i = 0; i < 8; ++i) Bs[lrow][lk + i] = f[i];
        __syncthreads();
        #pragma unroll
        for (int kk = 0; kk < 32; ++kk) {
            float a[4], b[4];
            #pragma unroll
            for (int i = 0; i < 4; ++i) a[i] = As[ty * 4 + i][kk];
            #pragma unroll
            for (int j = 0; j < 4; ++j) b[j] = Bs[tx * 4 + j][kk];
            #pragma unroll
            for (int i = 0; i < 4; ++i)
                #pragma unroll
                for (int j = 0; j < 4; ++j)
                    acc[i][j] += a[i] * b[j];
        }
        __syncthreads();
    }

    const int col0 = colbase + tx * 4;
    const int h = col0 >> 6, d = col0 & 63;   // 4 consecutive cols, one head
    #pragma unroll
    for (int i = 0; i < 4; ++i) {
        const int r = rowbase + ty * 4 + i;
        const int b = r >> 12, t = r & (T_SEQ - 1);
        bf16 pk[4];
        #pragma unroll
        for (int j = 0; j < 4; ++j) {
            float v = acc[i][j] + load_elem(bias, col0 + j);
            if (which != 2) v = (v > 0.f) ? (v + 1.f) : __expf(v);  // elu(v)+1
            pk[j] = __float2bfloat16(v);
        }
        *reinterpret_cast<uint2*>(outp + (((size_t)(b * NH + h)) * T_SEQ + t) * HD + d) =
            *reinterpret_cast<uint2*>(pk);
    }
}

// ---------------------------------------------------------------------------
// Kernel 2: per-chunk K^T V (64x64) and k column sums.  1024 blocks (bh,c).
// Mode-independent (reads bf16 staging).
// ---------------------------------------------------------------------------
__global__ __launch_bounds__(256) void chunk_kv(
    const bf16* __restrict__ Kf, const bf16* __restrict__ Vf,
    float* __restrict__ KV, float* __restrict__ ksum)
{
    const int bh = blockIdx.x >> 6;
    const int c  = blockIdx.x & 63;
    __shared__ float Ks[64][64];
    __shared__ float Vs[64][64];
    const int tid = threadIdx.x;
    const bf16* kp = Kf + ((size_t)bh * T_SEQ + c * CS) * HD;
    const bf16* vp = Vf + ((size_t)bh * T_SEQ + c * CS) * HD;
    #pragma unroll
    for (int j = 0; j < 2; ++j) {
        const int u = j * 256 + tid;         // uint4 index, 8 bf16 each
        float f[8];
        load8(kp, (size_t)u * 8, f);
        #pragma unroll
        for (int i = 0; i < 8; ++i) (&Ks[0][0])[u * 8 + i] = f[i];
        load8(vp, (size_t)u * 8, f);
        #pragma unroll
        for (int i = 0; i < 8; ++i) (&Vs[0][0])[u * 8 + i] = f[i];
    }
    __syncthreads();
    const int dv  = tid & 63;
    const int dk0 = (tid >> 6) * 16;   // wave-uniform
    float acc[16] = {};
    for (int t = 0; t < 64; ++t) {
        const float v = Vs[t][dv];
        const float4 k0 = *reinterpret_cast<const float4*>(&Ks[t][dk0 + 0]);
        const float4 k1 = *reinterpret_cast<const float4*>(&Ks[t][dk0 + 4]);
        const float4 k2 = *reinterpret_cast<const float4*>(&Ks[t][dk0 + 8]);
        const float4 k3 = *reinterpret_cast<const float4*>(&Ks[t][dk0 + 12]);
        acc[0]  += k0.x * v; acc[1]  += k0.y * v; acc[2]  += k0.z * v; acc[3]  += k0.w * v;
        acc[4]  += k1.x * v; acc[5]  += k1.y * v; acc[6]  += k1.z * v; acc[7]  += k1.w * v;
        acc[8]  += k2.x * v; acc[9]  += k2.y * v; acc[10] += k2.z * v; acc[11] += k2.w * v;
        acc[12] += k3.x * v; acc[13] += k3.y * v; acc[14] += k3.z * v; acc[15] += k3.w * v;
    }
    float* kvout = KV + ((size_t)bh * NCHUNK + c) * 4096;
    #pragma unroll
    for (int i = 0; i < 16; ++i) kvout[(dk0 + i) * 64 + dv] = acc[i];
    if (tid < 64) {
        float s = 0.f;
        for (int t = 0; t < 64; ++t) s += Ks[t][tid];
        ksum[((size_t)bh * NCHUNK + c) * 64 + tid] = s;
    }
}

// ---------------------------------------------------------------------------
// Kernel 3: in-place exclusive prefix over chunks (per head).  16 blocks.
// ---------------------------------------------------------------------------
__global__ __launch_bounds__(256) void prefix_kv(
    float* __restrict__ KV, float* __restrict__ ksum)
{
    const int bh = blockIdx.x;
    const int tid = threadIdx.x;
    float s[16];
    #pragma unroll
    for (int i = 0; i < 16; ++i) s[i] = 0.f;
    float z = 0.f;
    float* base = KV + (size_t)bh * NCHUNK * 4096;
    float* zb   = ksum + (size_t)bh * NCHUNK * 64;
    for (int c = 0; c < NCHUNK; ++c) {
        float* p = base + c * 4096;
        #pragma unroll
        for (int i = 0; i < 16; ++i) {
            const int idx = tid + i * 256;   // coalesced
            const float tmp = p[idx];
            p[idx] = s[i];
            s[i] += tmp;
        }
        if (tid < 64) {
            const float tmp = zb[c * 64 + tid];
            zb[c * 64 + tid] = z;
            z += tmp;
        }
    }
}

// ---------------------------------------------------------------------------
// Kernel 4: per-chunk attention output.  Mode-independent.
// O = masked(QK^T) V + Q @ S_prev ; den = rowsum + q.z_prev + eps
// ---------------------------------------------------------------------------
__global__ __launch_bounds__(256) void attn_chunk(
    const bf16* __restrict__ Qf, const bf16* __restrict__ Kf,
    const bf16* __restrict__ Vf, const float* __restrict__ KV,
    const float* __restrict__ ksum, bf16* __restrict__ Of)
{
    const int bh = blockIdx.x >> 6;
    const int c  = blockIdx.x & 63;
    const int b  = bh >> 3, h = bh & 7;
    __shared__ float Qs[64][65];   // padded: row-broadcast access
    __shared__ float KA[64][65];   // K tile, then reused for masked A
    __shared__ float Vs[64][64];
    __shared__ float zprev[64];
    __shared__ float rden[64];

    const int tid = threadIdx.x;
    const int tx = tid & 15, ty = tid >> 4;
    const size_t coff = ((size_t)bh * T_SEQ + c * CS) * HD;
    const float* Sp = KV + ((size_t)bh * NCHUNK + c) * 4096;

    #pragma unroll
    for (int j = 0; j < 2; ++j) {
        const int u  = j * 256 + tid;
        const int e0 = u * 8;
        const int r  = e0 >> 6, cc = e0 & 63;
        float f[8];
        load8(Qf + coff, (size_t)e0, f);
        #pragma unroll
        for (int i = 0; i < 8; ++i) Qs[r][cc + i] = f[i];
        load8(Kf + coff, (size_t)e0, f);
        #pragma unroll
        for (int i = 0; i < 8; ++i) KA[r][cc + i] = f[i];
        load8(Vf + coff, (size_t)e0, f);
        #pragma unroll
        for (int i = 0; i < 8; ++i) Vs[r][cc + i] = f[i];
    }
    if (tid < 64) zprev[tid] = ksum[((size_t)bh * NCHUNK + c) * 64 + tid];
    __syncthreads();

    // A = Q K^T
    float a[4][4] = {};
    for (int d = 0; d < 64; ++d) {
        float qa[4], kb[4];
        #pragma unroll
        for (int i = 0; i < 4; ++i) qa[i] = Qs[ty * 4 + i][d];
        #pragma unroll
        for (int j = 0; j < 4; ++j) kb[j] = KA[tx * 4 + j][d];
        #pragma unroll
        for (int i = 0; i < 4; ++i)
            #pragma unroll
            for (int j = 0; j < 4; ++j)
                a[i][j] += qa[i] * kb[j];
    }
    __syncthreads();
    #pragma unroll
    for (int i = 0; i < 4; ++i)
        #pragma unroll
        for (int j = 0; j < 4; ++j) {
            const int t = ty * 4 + i, s = tx * 4 + j;
            KA[t][s] = (s <= t) ? a[i][j] : 0.f;   // causal mask (inclusive)
        }
    __syncthreads();

    if (tid < 64) {
        float rs = 0.f;
        for (int s = 0; s < 64; ++s) rs += KA[tid][s];
        float dz = 0.f;
        for (int d = 0; d < 64; ++d) dz += Qs[tid][d] * zprev[d];
        rden[tid] = 1.f / (rs + dz + 1e-6f);
    }
    __syncthreads();

    float o[4][4] = {};
    for (int s = 0; s < 64; ++s) {
        float aa[4], vv[4];
        #pragma unroll
        for (int i = 0; i < 4; ++i) aa[i] = KA[ty * 4 + i][s];
        #pragma unroll
        for (int j = 0; j < 4; ++j) vv[j] = Vs[s][tx * 4 + j];
        #pragma unroll
        for (int i = 0; i < 4; ++i)
            #pragma unroll
            for (int j = 0; j < 4; ++j)
                o[i][j] += aa[i] * vv[j];
    }
    for (int d = 0; d < 64; ++d) {
        const float4 s4 = reinterpret_cast<const float4*>(Sp)[d * 16 + tx];
        #pragma unroll
        for (int i = 0; i < 4; ++i) {
            const float q = Qs[ty * 4 + i][d];
            o[i][0] += q * s4.x; o[i][1] += q * s4.y;
            o[i][2] += q * s4.z; o[i][3] += q * s4.w;
        }
    }

    #pragma unroll
    for (int i = 0; i < 4; ++i) {
        const int t  = ty * 4 + i;
        const int tg = c * CS + t;
        const float rd = rden[t];
        bf16 pk[4];
        pk[0] = __float2bfloat16(o[i][0] * rd);
        pk[1] = __float2bfloat16(o[i][1] * rd);
        pk[2] = __float2bfloat16(o[i][2] * rd);
        pk[3] = __float2bfloat16(o[i][3] * rd);
        bf16* op = Of + ((size_t)(b * T_SEQ + tg)) * EMB + h * HD + tx * 4;
        *reinterpret_cast<uint2*>(op) = *reinterpret_cast<uint2*>(pk);
    }
}

// ---------------------------------------------------------------------------
// Kernel 5: output projection.  out = Of @ Wo^T + bo.  Templated on dtype.
// ---------------------------------------------------------------------------
template <typename T>
__global__ __launch_bounds__(256) void out_proj(
    const int* __restrict__ flag,
    const bf16* __restrict__ A, const T* __restrict__ Wo,
    const T* __restrict__ bo, T* __restrict__ out)
{
    if (*flag != ModeOf<T>::v) return;

    __shared__ float As[64][33];
    __shared__ float Bs[64][33];
    const int tid = threadIdx.x;
    const int tx = tid & 15, ty = tid >> 4;
    const int rowbase = blockIdx.y * 64;
    const int colbase = blockIdx.x * 64;
    const int lrow = tid >> 2;
    const int lk   = (tid & 3) << 3;

    float acc[4][4] = {};

    for (int kt = 0; kt < EMB; kt += 32) {
        float f[8];
        load8(A, (size_t)(rowbase + lrow) * EMB + kt + lk, f);
        #pragma unroll
        for (int i = 0; i < 8; ++i) As[lrow][lk + i] = f[i];
        load8(Wo, (size_t)(colbase + lrow) * EMB + kt + lk, f);
        #pragma unroll
        for (int i = 0; i < 8; ++i) Bs[lrow][lk + i] = f[i];
        __syncthreads();
        #pragma unroll
        for (int kk = 0; kk < 32; ++kk) {
            float a[4], b[4];
            #pragma unroll
            for (int i = 0; i < 4; ++i) a[i] = As[ty * 4 + i][kk];
            #pragma unroll
            for (int j = 0; j < 4; ++j) b[j] = Bs[tx * 4 + j][kk];
            #pragma unroll
            for (int i = 0; i < 4; ++i)
                #pragma unroll
                for (int j = 0; j < 4; ++j)
                    acc[i][j] += a[i] * b[j];
        }
        __syncthreads();
    }

    #pragma unroll
    for (int j = 0; j < 4; ++j) {
        const int col = colbase + tx * 4 + j;
        const float bf = load_elem(bo, col);
        #pragma unroll
        for (int i = 0; i < 4; ++i) {
            const int r = rowbase + ty * 4 + i;
            store_elem(out, (size_t)r * EMB + col, acc[i][j] + bf);
        }
    }
}

// ---------------------------------------------------------------------------
extern "C" void kernel_launch(void* const* d_in, const int* in_sizes, int n_in,
                              void* d_out, int out_size, void* d_ws, size_t ws_size,
                              hipStream_t stream)
{
    // workspace layout (48.25 MB + 64 B):
    //   flag  : int (64 B reserved)
    //   Qf/Kf/Vf : bf16 (B,H,T,D) = 4,194,304 elems each (24 MB)
    //   KV    : fp32 (BH,NC,64,64) = 4,194,304            (16 MB)
    //   ksum  : fp32 (BH,NC,64)    = 65,536                (0.25 MB)
    //   Of    : bf16 (B,T,E)       = 4,194,304             (8 MB)
    int*  flag = (int*)d_ws;
    bf16* Qf = (bf16*)((char*)d_ws + 64);
    bf16* Kf = Qf + 4194304;
    bf16* Vf = Kf + 4194304;
    float* KV = (float*)(Vf + 4194304);
    float* ks = KV + 4194304;
    bf16* Of = (bf16*)(ks + 65536);

    detect_dtype<<<1, 64, 0, stream>>>((const unsigned short*)d_in[0], flag);

    // bf16-mode variant (no-ops if flag==1)
    qkv_gemm<bf16><<<dim3(8, 128, 3), 256, 0, stream>>>(flag,
        (const bf16*)d_in[0],
        (const bf16*)d_in[1], (const bf16*)d_in[2],
        (const bf16*)d_in[3], (const bf16*)d_in[4],
        (const bf16*)d_in[5], (const bf16*)d_in[6],
        Qf, Kf, Vf);
    // fp32-mode variant (no-ops if flag==0)
    qkv_gemm<float><<<dim3(8, 128, 3), 256, 0, stream>>>(flag,
        (const float*)d_in[0],
        (const float*)d_in[1], (const float*)d_in[2],
        (const float*)d_in[3], (const float*)d_in[4],
        (const float*)d_in[5], (const float*)d_in[6],
        Qf, Kf, Vf);

    chunk_kv<<<dim3(BHEADS * NCHUNK), 256, 0, stream>>>(Kf, Vf, KV, ks);
    prefix_kv<<<dim3(BHEADS), 256, 0, stream>>>(KV, ks);
    attn_chunk<<<dim3(BHEADS * NCHUNK), 256, 0, stream>>>(Qf, Kf, Vf, KV, ks, Of);

    out_proj<bf16><<<dim3(8, 128), 256, 0, stream>>>(flag,
        Of, (const bf16*)d_in[7], (const bf16*)d_in[8], (bf16*)d_out);
    out_proj<float><<<dim3(8, 128), 256, 0, stream>>>(flag,
        Of, (const float*)d_in[7], (const float*)d_in[8], (float*)d_out);
}

// Round 4
// 221.112 us; speedup vs baseline: 2.2651x; 2.2651x over previous
//
#include <hip/hip_runtime.h>
#include <hip/hip_bf16.h>

// Problem constants: B=2, T=4096, E=512, H=8, D=64
#define T_SEQ 4096
#define EMB   512
#define NH    8
#define HD    64
#define BATCH 2
#define M_ROWS (BATCH * T_SEQ)   // 8192
#define NCHUNK 64                // T / CS
#define CS     64                // chunk size
#define BHEADS (BATCH * NH)      // 16

using bf16 = __hip_bfloat16;
typedef __attribute__((ext_vector_type(8))) short short8;   // 8 bf16 = 4 VGPR
typedef __attribute__((ext_vector_type(4))) float floatx4;  // MFMA acc

__device__ __forceinline__ void bf2f(unsigned u, float& lo, float& hi) {
    lo = __uint_as_float((u & 0xffffu) << 16);
    hi = __uint_as_float(u & 0xffff0000u);
}

// --- dtype-polymorphic helpers (overload on pointer type) ------------------
__device__ __forceinline__ float load_elem(const bf16* p, size_t i) {
    return __bfloat162float(p[i]);
}
__device__ __forceinline__ float load_elem(const float* p, size_t i) {
    return p[i];
}
__device__ __forceinline__ void load8(const bf16* p, size_t off, float* f) {
    uint4 u = *reinterpret_cast<const uint4*>(p + off);
    bf2f(u.x, f[0], f[1]); bf2f(u.y, f[2], f[3]);
    bf2f(u.z, f[4], f[5]); bf2f(u.w, f[6], f[7]);
}
__device__ __forceinline__ void load8(const float* p, size_t off, float* f) {
    float4 a = *reinterpret_cast<const float4*>(p + off);
    float4 b = *reinterpret_cast<const float4*>(p + off + 4);
    f[0] = a.x; f[1] = a.y; f[2] = a.z; f[3] = a.w;
    f[4] = b.x; f[5] = b.y; f[6] = b.z; f[7] = b.w;
}
__device__ __forceinline__ void store_elem(bf16* p, size_t i, float v) {
    p[i] = __float2bfloat16(v);
}
__device__ __forceinline__ void store_elem(float* p, size_t i, float v) {
    p[i] = v;
}
__device__ __forceinline__ short f2bs(float f) {
    bf16 h = __float2bfloat16(f);
    return *reinterpret_cast<short*>(&h);
}
// stage 8 consecutive elems from global (any dtype) to LDS as bf16 (16B write)
__device__ __forceinline__ void stage8(const bf16* g, short* l) {
    *reinterpret_cast<short8*>(l) = *reinterpret_cast<const short8*>(g);
}
__device__ __forceinline__ void stage8(const float* g, short* l) {
    float4 a = *reinterpret_cast<const float4*>(g);
    float4 b = *reinterpret_cast<const float4*>(g + 4);
    short8 v;
    v[0] = f2bs(a.x); v[1] = f2bs(a.y); v[2] = f2bs(a.z); v[3] = f2bs(a.w);
    v[4] = f2bs(b.x); v[5] = f2bs(b.y); v[6] = f2bs(b.z); v[7] = f2bs(b.w);
    *reinterpret_cast<short8*>(l) = v;
}
template <typename T> struct ModeOf { static constexpr int v = 0; };  // bf16
template <> struct ModeOf<float>    { static constexpr int v = 1; };  // fp32

#define LDSTR 72   // LDS row stride in shorts: 144 B = 9 banks/row, gcd(9,32)=1

// ---------------------------------------------------------------------------
// Kernel 0: dtype detector (unchanged, validated round 3).
// ---------------------------------------------------------------------------
__global__ void detect_dtype(const unsigned short* __restrict__ xraw,
                             int* __restrict__ flag)
{
    const int lane = threadIdx.x;   // 64 threads
    bool bad = false;
    for (int i = 0; i < 64; ++i) {
        const unsigned u = xraw[(size_t)(lane + i * 64) * 2];  // even halves
        const float f = __uint_as_float(u << 16);
        if (!(fabsf(f) <= 1e9f)) bad = true;   // catches NaN/inf/huge
    }
    const unsigned long long m = __ballot(bad);
    if (lane == 0) *flag = (m != 0ull) ? 1 : 0;
}

// ---------------------------------------------------------------------------
// Kernel 1: fused QKV projection via MFMA 16x16x32 bf16.
// C = x @ W^T (+bias, elu+1 on Q/K).  Both operands K-major (B^T-input GEMM).
// Block = 256 thr = 4 waves, tile 128x128, wave tile 64x64 (4x4 MFMA frags),
// BK=64.  blockIdx.y: 0-3 -> Q cols, 4-7 -> K, 8-11 -> V.
// Output (B,H,T,D) bf16.
// ---------------------------------------------------------------------------
template <typename T>
__global__ __launch_bounds__(256) void qkv_mfma(
    const int* __restrict__ flag,
    const T* __restrict__ x,
    const T* __restrict__ Wq, const T* __restrict__ bq,
    const T* __restrict__ Wk, const T* __restrict__ bk,
    const T* __restrict__ Wv, const T* __restrict__ bv,
    bf16* __restrict__ Qf, bf16* __restrict__ Kf, bf16* __restrict__ Vf)
{
    if (*flag != ModeOf<T>::v) return;

    const int mtile = blockIdx.x;            // 0..63
    const int ntile = blockIdx.y;            // 0..11
    const int which = ntile >> 2;
    const T* W    = (which == 0) ? Wq : ((which == 1) ? Wk : Wv);
    const T* bias = (which == 0) ? bq : ((which == 1) ? bk : bv);
    bf16* outp    = (which == 0) ? Qf : ((which == 1) ? Kf : Vf);
    const int nbase = (ntile & 3) * 128;     // col base within this W
    const int mbase = mtile * 128;

    __shared__ short As[128 * LDSTR];
    __shared__ short Bs[128 * LDSTR];

    const int tid  = threadIdx.x;
    const int wave = tid >> 6, lane = tid & 63;
    const int wm = wave >> 1, wn = wave & 1;
    const int lm = lane & 15, quad = lane >> 4;

    floatx4 acc[4][4];
    const floatx4 zero = {0.f, 0.f, 0.f, 0.f};
    #pragma unroll
    for (int mt = 0; mt < 4; ++mt)
        #pragma unroll
        for (int nt = 0; nt < 4; ++nt) acc[mt][nt] = zero;

    for (int kt = 0; kt < EMB; kt += 64) {
        #pragma unroll
        for (int i = 0; i < 4; ++i) {
            const int c = tid + i * 256;          // 0..1023 chunk of 8
            const int row = c >> 3, k8 = (c & 7) * 8;
            stage8(x + (size_t)(mbase + row) * EMB + kt + k8, &As[row * LDSTR + k8]);
            stage8(W + (size_t)(nbase + row) * EMB + kt + k8, &Bs[row * LDSTR + k8]);
        }
        __syncthreads();
        #pragma unroll
        for (int ks = 0; ks < 2; ++ks) {
            short8 af[4], bfr[4];
            #pragma unroll
            for (int mt = 0; mt < 4; ++mt)
                af[mt] = *reinterpret_cast<const short8*>(
                    &As[(wm * 64 + mt * 16 + lm) * LDSTR + ks * 32 + quad * 8]);
            #pragma unroll
            for (int nt = 0; nt < 4; ++nt)
                bfr[nt] = *reinterpret_cast<const short8*>(
                    &Bs[(wn * 64 + nt * 16 + lm) * LDSTR + ks * 32 + quad * 8]);
            #pragma unroll
            for (int mt = 0; mt < 4; ++mt)
                #pragma unroll
                for (int nt = 0; nt < 4; ++nt)
                    acc[mt][nt] = __builtin_amdgcn_mfma_f32_16x16x32_bf16(
                        af[mt], bfr[nt], acc[mt][nt], 0, 0, 0);
        }
        __syncthreads();
    }

    // epilogue: C/D layout col=lane&15, row=quad*4+reg  [m89/m91 verified]
    #pragma unroll
    for (int nt = 0; nt < 4; ++nt) {
        const int col = nbase + wn * 64 + nt * 16 + lm;   // 0..511 in this W
        const float bv_ = load_elem(bias, col);
        const int h = col >> 6, d = col & 63;
        #pragma unroll
        for (int mt = 0; mt < 4; ++mt)
            #pragma unroll
            for (int r = 0; r < 4; ++r) {
                const int row = mbase + wm * 64 + mt * 16 + quad * 4 + r;
                const int b = row >> 12, t = row & (T_SEQ - 1);
                float v = acc[mt][nt][r] + bv_;
                if (which != 2) v = (v > 0.f) ? (v + 1.f) : __expf(v);  // elu+1
                outp[(((size_t)(b * NH + h)) * T_SEQ + t) * HD + d] = __float2bfloat16(v);
            }
    }
}

// ---------------------------------------------------------------------------
// Kernel 2: per-chunk K^T V (64x64) and k column sums.  1024 blocks (bh,c).
// ---------------------------------------------------------------------------
__global__ __launch_bounds__(256) void chunk_kv(
    const bf16* __restrict__ Kf, const bf16* __restrict__ Vf,
    float* __restrict__ KV, float* __restrict__ ksum)
{
    const int bh = blockIdx.x >> 6;
    const int c  = blockIdx.x & 63;
    __shared__ float Ks[64][64];
    __shared__ float Vs[64][64];
    const int tid = threadIdx.x;
    const bf16* kp = Kf + ((size_t)bh * T_SEQ + c * CS) * HD;
    const bf16* vp = Vf + ((size_t)bh * T_SEQ + c * CS) * HD;
    #pragma unroll
    for (int j = 0; j < 2; ++j) {
        const int u = j * 256 + tid;
        float f[8];
        load8(kp, (size_t)u * 8, f);
        #pragma unroll
        for (int i = 0; i < 8; ++i) (&Ks[0][0])[u * 8 + i] = f[i];
        load8(vp, (size_t)u * 8, f);
        #pragma unroll
        for (int i = 0; i < 8; ++i) (&Vs[0][0])[u * 8 + i] = f[i];
    }
    __syncthreads();
    const int dv  = tid & 63;
    const int dk0 = (tid >> 6) * 16;
    float acc[16] = {};
    for (int t = 0; t < 64; ++t) {
        const float v = Vs[t][dv];
        const float4 k0 = *reinterpret_cast<const float4*>(&Ks[t][dk0 + 0]);
        const float4 k1 = *reinterpret_cast<const float4*>(&Ks[t][dk0 + 4]);
        const float4 k2 = *reinterpret_cast<const float4*>(&Ks[t][dk0 + 8]);
        const float4 k3 = *reinterpret_cast<const float4*>(&Ks[t][dk0 + 12]);
        acc[0]  += k0.x * v; acc[1]  += k0.y * v; acc[2]  += k0.z * v; acc[3]  += k0.w * v;
        acc[4]  += k1.x * v; acc[5]  += k1.y * v; acc[6]  += k1.z * v; acc[7]  += k1.w * v;
        acc[8]  += k2.x * v; acc[9]  += k2.y * v; acc[10] += k2.z * v; acc[11] += k2.w * v;
        acc[12] += k3.x * v; acc[13] += k3.y * v; acc[14] += k3.z * v; acc[15] += k3.w * v;
    }
    float* kvout = KV + ((size_t)bh * NCHUNK + c) * 4096;
    #pragma unroll
    for (int i = 0; i < 16; ++i) kvout[(dk0 + i) * 64 + dv] = acc[i];
    if (tid < 64) {
        float s = 0.f;
        for (int t = 0; t < 64; ++t) s += Ks[t][tid];
        ksum[((size_t)bh * NCHUNK + c) * 64 + tid] = s;
    }
}

// ---------------------------------------------------------------------------
// Kernel 3: in-place exclusive prefix over chunks (per head).  16 blocks.
// ---------------------------------------------------------------------------
__global__ __launch_bounds__(256) void prefix_kv(
    float* __restrict__ KV, float* __restrict__ ksum)
{
    const int bh = blockIdx.x;
    const int tid = threadIdx.x;
    float s[16];
    #pragma unroll
    for (int i = 0; i < 16; ++i) s[i] = 0.f;
    float z = 0.f;
    float* base = KV + (size_t)bh * NCHUNK * 4096;
    float* zb   = ksum + (size_t)bh * NCHUNK * 64;
    for (int c = 0; c < NCHUNK; ++c) {
        float* p = base + c * 4096;
        #pragma unroll
        for (int i = 0; i < 16; ++i) {
            const int idx = tid + i * 256;
            const float tmp = p[idx];
            p[idx] = s[i];
            s[i] += tmp;
        }
        if (tid < 64) {
            const float tmp = zb[c * 64 + tid];
            zb[c * 64 + tid] = z;
            z += tmp;
        }
    }
}

// ---------------------------------------------------------------------------
// Kernel 4: per-chunk attention output (unchanged, validated round 3).
// ---------------------------------------------------------------------------
__global__ __launch_bounds__(256) void attn_chunk(
    const bf16* __restrict__ Qf, const bf16* __restrict__ Kf,
    const bf16* __restrict__ Vf, const float* __restrict__ KV,
    const float* __restrict__ ksum, bf16* __restrict__ Of)
{
    const int bh = blockIdx.x >> 6;
    const int c  = blockIdx.x & 63;
    const int b  = bh >> 3, h = bh & 7;
    __shared__ float Qs[64][65];
    __shared__ float KA[64][65];
    __shared__ float Vs[64][64];
    __shared__ float zprev[64];
    __shared__ float rden[64];

    const int tid = threadIdx.x;
    const int tx = tid & 15, ty = tid >> 4;
    const size_t coff = ((size_t)bh * T_SEQ + c * CS) * HD;
    const float* Sp = KV + ((size_t)bh * NCHUNK + c) * 4096;

    #pragma unroll
    for (int j = 0; j < 2; ++j) {
        const int u  = j * 256 + tid;
        const int e0 = u * 8;
        const int r  = e0 >> 6, cc = e0 & 63;
        float f[8];
        load8(Qf + coff, (size_t)e0, f);
        #pragma unroll
        for (int i = 0; i < 8; ++i) Qs[r][cc + i] = f[i];
        load8(Kf + coff, (size_t)e0, f);
        #pragma unroll
        for (int i = 0; i < 8; ++i) KA[r][cc + i] = f[i];
        load8(Vf + coff, (size_t)e0, f);
        #pragma unroll
        for (int i = 0; i < 8; ++i) Vs[r][cc + i] = f[i];
    }
    if (tid < 64) zprev[tid] = ksum[((size_t)bh * NCHUNK + c) * 64 + tid];
    __syncthreads();

    float a[4][4] = {};
    for (int d = 0; d < 64; ++d) {
        float qa[4], kb[4];
        #pragma unroll
        for (int i = 0; i < 4; ++i) qa[i] = Qs[ty * 4 + i][d];
        #pragma unroll
        for (int j = 0; j < 4; ++j) kb[j] = KA[tx * 4 + j][d];
        #pragma unroll
        for (int i = 0; i < 4; ++i)
            #pragma unroll
            for (int j = 0; j < 4; ++j)
                a[i][j] += qa[i] * kb[j];
    }
    __syncthreads();
    #pragma unroll
    for (int i = 0; i < 4; ++i)
        #pragma unroll
        for (int j = 0; j < 4; ++j) {
            const int t = ty * 4 + i, s = tx * 4 + j;
            KA[t][s] = (s <= t) ? a[i][j] : 0.f;
        }
    __syncthreads();

    if (tid < 64) {
        float rs = 0.f;
        for (int s = 0; s < 64; ++s) rs += KA[tid][s];
        float dz = 0.f;
        for (int d = 0; d < 64; ++d) dz += Qs[tid][d] * zprev[d];
        rden[tid] = 1.f / (rs + dz + 1e-6f);
    }
    __syncthreads();

    float o[4][4] = {};
    for (int s = 0; s < 64; ++s) {
        float aa[4], vv[4];
        #pragma unroll
        for (int i = 0; i < 4; ++i) aa[i] = KA[ty * 4 + i][s];
        #pragma unroll
        for (int j = 0; j < 4; ++j) vv[j] = Vs[s][tx * 4 + j];
        #pragma unroll
        for (int i = 0; i < 4; ++i)
            #pragma unroll
            for (int j = 0; j < 4; ++j)
                o[i][j] += aa[i] * vv[j];
    }
    for (int d = 0; d < 64; ++d) {
        const float4 s4 = reinterpret_cast<const float4*>(Sp)[d * 16 + tx];
        #pragma unroll
        for (int i = 0; i < 4; ++i) {
            const float q = Qs[ty * 4 + i][d];
            o[i][0] += q * s4.x; o[i][1] += q * s4.y;
            o[i][2] += q * s4.z; o[i][3] += q * s4.w;
        }
    }

    #pragma unroll
    for (int i = 0; i < 4; ++i) {
        const int t  = ty * 4 + i;
        const int tg = c * CS + t;
        const float rd = rden[t];
        bf16 pk[4];
        pk[0] = __float2bfloat16(o[i][0] * rd);
        pk[1] = __float2bfloat16(o[i][1] * rd);
        pk[2] = __float2bfloat16(o[i][2] * rd);
        pk[3] = __float2bfloat16(o[i][3] * rd);
        bf16* op = Of + ((size_t)(b * T_SEQ + tg)) * EMB + h * HD + tx * 4;
        *reinterpret_cast<uint2*>(op) = *reinterpret_cast<uint2*>(pk);
    }
}

// ---------------------------------------------------------------------------
// Kernel 5: output projection via MFMA.  out = Of @ Wo^T + bo.
// Same structure as qkv_mfma; grid (64, 4).
// ---------------------------------------------------------------------------
template <typename T>
__global__ __launch_bounds__(256) void out_proj_mfma(
    const int* __restrict__ flag,
    const bf16* __restrict__ A, const T* __restrict__ Wo,
    const T* __restrict__ bo, T* __restrict__ out)
{
    if (*flag != ModeOf<T>::v) return;

    const int mbase = blockIdx.x * 128;
    const int nbase = blockIdx.y * 128;

    __shared__ short As[128 * LDSTR];
    __shared__ short Bs[128 * LDSTR];

    const int tid  = threadIdx.x;
    const int wave = tid >> 6, lane = tid & 63;
    const int wm = wave >> 1, wn = wave & 1;
    const int lm = lane & 15, quad = lane >> 4;

    floatx4 acc[4][4];
    const floatx4 zero = {0.f, 0.f, 0.f, 0.f};
    #pragma unroll
    for (int mt = 0; mt < 4; ++mt)
        #pragma unroll
        for (int nt = 0; nt < 4; ++nt) acc[mt][nt] = zero;

    for (int kt = 0; kt < EMB; kt += 64) {
        #pragma unroll
        for (int i = 0; i < 4; ++i) {
            const int c = tid + i * 256;
            const int row = c >> 3, k8 = (c & 7) * 8;
            stage8(A  + (size_t)(mbase + row) * EMB + kt + k8, &As[row * LDSTR + k8]);
            stage8(Wo + (size_t)(nbase + row) * EMB + kt + k8, &Bs[row * LDSTR + k8]);
        }
        __syncthreads();
        #pragma unroll
        for (int ks = 0; ks < 2; ++ks) {
            short8 af[4], bfr[4];
            #pragma unroll
            for (int mt = 0; mt < 4; ++mt)
                af[mt] = *reinterpret_cast<const short8*>(
                    &As[(wm * 64 + mt * 16 + lm) * LDSTR + ks * 32 + quad * 8]);
            #pragma unroll
            for (int nt = 0; nt < 4; ++nt)
                bfr[nt] = *reinterpret_cast<const short8*>(
                    &Bs[(wn * 64 + nt * 16 + lm) * LDSTR + ks * 32 + quad * 8]);
            #pragma unroll
            for (int mt = 0; mt < 4; ++mt)
                #pragma unroll
                for (int nt = 0; nt < 4; ++nt)
                    acc[mt][nt] = __builtin_amdgcn_mfma_f32_16x16x32_bf16(
                        af[mt], bfr[nt], acc[mt][nt], 0, 0, 0);
        }
        __syncthreads();
    }

    #pragma unroll
    for (int nt = 0; nt < 4; ++nt) {
        const int col = nbase + wn * 64 + nt * 16 + lm;
        const float bv_ = load_elem(bo, col);
        #pragma unroll
        for (int mt = 0; mt < 4; ++mt)
            #pragma unroll
            for (int r = 0; r < 4; ++r) {
                const int row = mbase + wm * 64 + mt * 16 + quad * 4 + r;
                store_elem(out, (size_t)row * EMB + col, acc[mt][nt][r] + bv_);
            }
    }
}

// ---------------------------------------------------------------------------
extern "C" void kernel_launch(void* const* d_in, const int* in_sizes, int n_in,
                              void* d_out, int out_size, void* d_ws, size_t ws_size,
                              hipStream_t stream)
{
    // workspace layout (48.25 MB + 64 B — validated round 3):
    //   flag  : int (64 B reserved)
    //   Qf/Kf/Vf : bf16 (B,H,T,D) = 4,194,304 elems each (24 MB)
    //   KV    : fp32 (BH,NC,64,64) = 4,194,304            (16 MB)
    //   ksum  : fp32 (BH,NC,64)    = 65,536                (0.25 MB)
    //   Of    : bf16 (B,T,E)       = 4,194,304             (8 MB)
    int*  flag = (int*)d_ws;
    bf16* Qf = (bf16*)((char*)d_ws + 64);
    bf16* Kf = Qf + 4194304;
    bf16* Vf = Kf + 4194304;
    float* KV = (float*)(Vf + 4194304);
    float* ks = KV + 4194304;
    bf16* Of = (bf16*)(ks + 65536);

    detect_dtype<<<1, 64, 0, stream>>>((const unsigned short*)d_in[0], flag);

    qkv_mfma<bf16><<<dim3(64, 12), 256, 0, stream>>>(flag,
        (const bf16*)d_in[0],
        (const bf16*)d_in[1], (const bf16*)d_in[2],
        (const bf16*)d_in[3], (const bf16*)d_in[4],
        (const bf16*)d_in[5], (const bf16*)d_in[6],
        Qf, Kf, Vf);
    qkv_mfma<float><<<dim3(64, 12), 256, 0, stream>>>(flag,
        (const float*)d_in[0],
        (const float*)d_in[1], (const float*)d_in[2],
        (const float*)d_in[3], (const float*)d_in[4],
        (const float*)d_in[5], (const float*)d_in[6],
        Qf, Kf, Vf);

    chunk_kv<<<dim3(BHEADS * NCHUNK), 256, 0, stream>>>(Kf, Vf, KV, ks);
    prefix_kv<<<dim3(BHEADS), 256, 0, stream>>>(KV, ks);
    attn_chunk<<<dim3(BHEADS * NCHUNK), 256, 0, stream>>>(Qf, Kf, Vf, KV, ks, Of);

    out_proj_mfma<bf16><<<dim3(64, 4), 256, 0, stream>>>(flag,
        Of, (const bf16*)d_in[7], (const bf16*)d_in[8], (bf16*)d_out);
    out_proj_mfma<float><<<dim3(64, 4), 256, 0, stream>>>(flag,
        Of, (const float*)d_in[7], (const float*)d_in[8], (float*)d_out);
}

// Round 5
// 171.811 us; speedup vs baseline: 2.9151x; 1.2869x over previous
//
#include <hip/hip_runtime.h>
#include <hip/hip_bf16.h>

// Problem constants: B=2, T=4096, E=512, H=8, D=64
#define T_SEQ 4096
#define EMB   512
#define NH    8
#define HD    64
#define BATCH 2
#define M_ROWS (BATCH * T_SEQ)   // 8192
#define NCHUNK 64                // T / CS
#define CS     64                // chunk size
#define BHEADS (BATCH * NH)      // 16

using bf16 = __hip_bfloat16;
typedef __attribute__((ext_vector_type(8))) short short8;   // 8 bf16 = 4 VGPR
typedef __attribute__((ext_vector_type(4))) float floatx4;  // MFMA acc

__device__ __forceinline__ void bf2f(unsigned u, float& lo, float& hi) {
    lo = __uint_as_float((u & 0xffffu) << 16);
    hi = __uint_as_float(u & 0xffff0000u);
}
__device__ __forceinline__ float bs2f(short s) {
    return __uint_as_float(((unsigned)(unsigned short)s) << 16);
}

// --- dtype-polymorphic helpers (overload on pointer type) ------------------
__device__ __forceinline__ float load_elem(const bf16* p, size_t i) {
    return __bfloat162float(p[i]);
}
__device__ __forceinline__ float load_elem(const float* p, size_t i) {
    return p[i];
}
__device__ __forceinline__ void store_elem(bf16* p, size_t i, float v) {
    p[i] = __float2bfloat16(v);
}
__device__ __forceinline__ void store_elem(float* p, size_t i, float v) {
    p[i] = v;
}
__device__ __forceinline__ short f2bs(float f) {
    bf16 h = __float2bfloat16(f);
    return *reinterpret_cast<short*>(&h);
}
// stage 8 consecutive elems from global (any dtype) to LDS as bf16 (16B write)
__device__ __forceinline__ void stage8(const bf16* g, short* l) {
    *reinterpret_cast<short8*>(l) = *reinterpret_cast<const short8*>(g);
}
__device__ __forceinline__ void stage8(const float* g, short* l) {
    float4 a = *reinterpret_cast<const float4*>(g);
    float4 b = *reinterpret_cast<const float4*>(g + 4);
    short8 v;
    v[0] = f2bs(a.x); v[1] = f2bs(a.y); v[2] = f2bs(a.z); v[3] = f2bs(a.w);
    v[4] = f2bs(b.x); v[5] = f2bs(b.y); v[6] = f2bs(b.z); v[7] = f2bs(b.w);
    *reinterpret_cast<short8*>(l) = v;
}
template <typename T> struct ModeOf { static constexpr int v = 0; };  // bf16
template <> struct ModeOf<float>    { static constexpr int v = 1; };  // fp32

#define LDSTR 72   // LDS row stride in shorts: 144 B (16B-aligned rows for b128)

// ---------------------------------------------------------------------------
// Kernel 0: dtype detector (validated round 3).
// ---------------------------------------------------------------------------
__global__ void detect_dtype(const unsigned short* __restrict__ xraw,
                             int* __restrict__ flag)
{
    const int lane = threadIdx.x;   // 64 threads
    bool bad = false;
    for (int i = 0; i < 64; ++i) {
        const unsigned u = xraw[(size_t)(lane + i * 64) * 2];  // even halves
        const float f = __uint_as_float(u << 16);
        if (!(fabsf(f) <= 1e9f)) bad = true;   // catches NaN/inf/huge
    }
    const unsigned long long m = __ballot(bad);
    if (lane == 0) *flag = (m != 0ull) ? 1 : 0;
}

// ---------------------------------------------------------------------------
// Kernel 1: fused QKV projection via MFMA 16x16x32 bf16 (validated round 4).
// ---------------------------------------------------------------------------
template <typename T>
__global__ __launch_bounds__(256) void qkv_mfma(
    const int* __restrict__ flag,
    const T* __restrict__ x,
    const T* __restrict__ Wq, const T* __restrict__ bq,
    const T* __restrict__ Wk, const T* __restrict__ bk,
    const T* __restrict__ Wv, const T* __restrict__ bv,
    bf16* __restrict__ Qf, bf16* __restrict__ Kf, bf16* __restrict__ Vf)
{
    if (*flag != ModeOf<T>::v) return;

    const int mtile = blockIdx.x;            // 0..63
    const int ntile = blockIdx.y;            // 0..11
    const int which = ntile >> 2;
    const T* W    = (which == 0) ? Wq : ((which == 1) ? Wk : Wv);
    const T* bias = (which == 0) ? bq : ((which == 1) ? bk : bv);
    bf16* outp    = (which == 0) ? Qf : ((which == 1) ? Kf : Vf);
    const int nbase = (ntile & 3) * 128;     // col base within this W
    const int mbase = mtile * 128;

    __shared__ short As[128 * LDSTR];
    __shared__ short Bs[128 * LDSTR];

    const int tid  = threadIdx.x;
    const int wave = tid >> 6, lane = tid & 63;
    const int wm = wave >> 1, wn = wave & 1;
    const int lm = lane & 15, quad = lane >> 4;

    floatx4 acc[4][4];
    const floatx4 zero = {0.f, 0.f, 0.f, 0.f};
    #pragma unroll
    for (int mt = 0; mt < 4; ++mt)
        #pragma unroll
        for (int nt = 0; nt < 4; ++nt) acc[mt][nt] = zero;

    for (int kt = 0; kt < EMB; kt += 64) {
        #pragma unroll
        for (int i = 0; i < 4; ++i) {
            const int c = tid + i * 256;          // 0..1023 chunk of 8
            const int row = c >> 3, k8 = (c & 7) * 8;
            stage8(x + (size_t)(mbase + row) * EMB + kt + k8, &As[row * LDSTR + k8]);
            stage8(W + (size_t)(nbase + row) * EMB + kt + k8, &Bs[row * LDSTR + k8]);
        }
        __syncthreads();
        #pragma unroll
        for (int ks = 0; ks < 2; ++ks) {
            short8 af[4], bfr[4];
            #pragma unroll
            for (int mt = 0; mt < 4; ++mt)
                af[mt] = *reinterpret_cast<const short8*>(
                    &As[(wm * 64 + mt * 16 + lm) * LDSTR + ks * 32 + quad * 8]);
            #pragma unroll
            for (int nt = 0; nt < 4; ++nt)
                bfr[nt] = *reinterpret_cast<const short8*>(
                    &Bs[(wn * 64 + nt * 16 + lm) * LDSTR + ks * 32 + quad * 8]);
            #pragma unroll
            for (int mt = 0; mt < 4; ++mt)
                #pragma unroll
                for (int nt = 0; nt < 4; ++nt)
                    acc[mt][nt] = __builtin_amdgcn_mfma_f32_16x16x32_bf16(
                        af[mt], bfr[nt], acc[mt][nt], 0, 0, 0);
        }
        __syncthreads();
    }

    #pragma unroll
    for (int nt = 0; nt < 4; ++nt) {
        const int col = nbase + wn * 64 + nt * 16 + lm;   // 0..511 in this W
        const float bv_ = load_elem(bias, col);
        const int h = col >> 6, d = col & 63;
        #pragma unroll
        for (int mt = 0; mt < 4; ++mt)
            #pragma unroll
            for (int r = 0; r < 4; ++r) {
                const int row = mbase + wm * 64 + mt * 16 + quad * 4 + r;
                const int b = row >> 12, t = row & (T_SEQ - 1);
                float v = acc[mt][nt][r] + bv_;
                if (which != 2) v = (v > 0.f) ? (v + 1.f) : __expf(v);  // elu+1
                outp[(((size_t)(b * NH + h)) * T_SEQ + t) * HD + d] = __float2bfloat16(v);
            }
    }
}

// ---------------------------------------------------------------------------
// Kernel 2: per-chunk K^T V via MFMA + k column sums.  1024 blocks (bh,c).
// C[dk][dv] = sum_s K[s][dk] V[s][dv]: both operands transposed-staged
// ([d][s], stride 72 keeps b128 aligned; 8-way write conflict accepted).
// ---------------------------------------------------------------------------
__global__ __launch_bounds__(256) void chunk_kv(
    const bf16* __restrict__ Kf, const bf16* __restrict__ Vf,
    float* __restrict__ KV, float* __restrict__ ksum)
{
    const int bh = blockIdx.x >> 6;
    const int c  = blockIdx.x & 63;
    __shared__ short Kt[64 * LDSTR];   // Kt[d][s]
    __shared__ short Vt[64 * LDSTR];   // Vt[d][s]
    const int tid = threadIdx.x;
    const bf16* kp = Kf + ((size_t)bh * T_SEQ + c * CS) * HD;
    const bf16* vp = Vf + ((size_t)bh * T_SEQ + c * CS) * HD;

    #pragma unroll
    for (int j = 0; j < 2; ++j) {
        const int u = j * 256 + tid;        // 0..511 chunks of 8 along d
        const int e0 = u * 8;
        const int s = e0 >> 6, d0 = e0 & 63;
        short8 ku = *reinterpret_cast<const short8*>(kp + e0);
        short8 vu = *reinterpret_cast<const short8*>(vp + e0);
        #pragma unroll
        for (int i = 0; i < 8; ++i) {
            Kt[(d0 + i) * LDSTR + s] = ku[i];
            Vt[(d0 + i) * LDSTR + s] = vu[i];
        }
    }
    __syncthreads();

    const int w = tid >> 6, lane = tid & 63;
    const int lm = lane & 15, quad = lane >> 4;

    floatx4 acc[4];
    const floatx4 zero = {0.f, 0.f, 0.f, 0.f};
    #pragma unroll
    for (int nt = 0; nt < 4; ++nt) acc[nt] = zero;

    #pragma unroll
    for (int ks = 0; ks < 2; ++ks) {
        short8 ak = *reinterpret_cast<const short8*>(
            &Kt[(w * 16 + lm) * LDSTR + ks * 32 + quad * 8]);
        #pragma unroll
        for (int nt = 0; nt < 4; ++nt) {
            short8 bv = *reinterpret_cast<const short8*>(
                &Vt[(nt * 16 + lm) * LDSTR + ks * 32 + quad * 8]);
            acc[nt] = __builtin_amdgcn_mfma_f32_16x16x32_bf16(ak, bv, acc[nt], 0, 0, 0);
        }
    }

    float* kvout = KV + ((size_t)bh * NCHUNK + c) * 4096;
    #pragma unroll
    for (int nt = 0; nt < 4; ++nt)
        #pragma unroll
        for (int r = 0; r < 4; ++r) {
            const int dk = w * 16 + quad * 4 + r;
            const int dv = nt * 16 + lm;
            kvout[dk * 64 + dv] = acc[nt][r];
        }

    if (tid < 64) {   // ksum[d] = sum_s K[s][d] = row-sum of Kt
        float s = 0.f;
        #pragma unroll 8
        for (int t = 0; t < 64; ++t) s += bs2f(Kt[tid * LDSTR + t]);
        ksum[((size_t)bh * NCHUNK + c) * 64 + tid] = s;
    }
}

// ---------------------------------------------------------------------------
// Kernel 3: exclusive prefix over chunks — element-parallel register scan.
// Grid 256 blocks (bh, part) x 256 threads; each thread scans one of the
// 4096 state elements across 64 chunks (batched loads for MLP).
// Block (part==0) lane<64 also scans the 64-elem ksum state.
// ---------------------------------------------------------------------------
__global__ __launch_bounds__(256) void prefix_kv(
    float* __restrict__ KV, float* __restrict__ ksum)
{
    const int bh   = blockIdx.x >> 4;
    const int part = blockIdx.x & 15;
    const int tid  = threadIdx.x;
    const int e    = part * 256 + tid;   // 0..4095
    float* base = KV + (size_t)bh * NCHUNK * 4096 + e;

    float s = 0.f;
    #pragma unroll
    for (int cb = 0; cb < 4; ++cb) {
        float v[16];
        #pragma unroll
        for (int i = 0; i < 16; ++i) v[i] = base[(size_t)(cb * 16 + i) * 4096];
        #pragma unroll
        for (int i = 0; i < 16; ++i) {
            const float tmp = v[i];
            base[(size_t)(cb * 16 + i) * 4096] = s;
            s += tmp;
        }
    }

    if (part == 0 && tid < 64) {
        float* zb = ksum + (size_t)bh * NCHUNK * 64 + tid;
        float z = 0.f;
        #pragma unroll
        for (int cb = 0; cb < 4; ++cb) {
            float v[16];
            #pragma unroll
            for (int i = 0; i < 16; ++i) v[i] = zb[(size_t)(cb * 16 + i) * 64];
            #pragma unroll
            for (int i = 0; i < 16; ++i) {
                const float tmp = v[i];
                zb[(size_t)(cb * 16 + i) * 64] = z;
                z += tmp;
            }
        }
    }
}

// ---------------------------------------------------------------------------
// Kernel 4: per-chunk attention output via MFMA.
// P = mask(Q K^T) via MFMA -> LDS (bf16); O = P V (MFMA) + Q S_prev (scalar
// fp32); den = rowsum(P) + q.z_prev + eps.  1024 blocks (bh,c).
// ---------------------------------------------------------------------------
__global__ __launch_bounds__(256) void attn_mfma(
    const bf16* __restrict__ Qf, const bf16* __restrict__ Kf,
    const bf16* __restrict__ Vf, const float* __restrict__ KV,
    const float* __restrict__ ksum, bf16* __restrict__ Of)
{
    const int bh = blockIdx.x >> 6;
    const int c  = blockIdx.x & 63;
    const int b  = bh >> 3, h = bh & 7;

    __shared__ short Qs [64 * LDSTR];  // Q[t][d]
    __shared__ short Ksn[64 * LDSTR];  // K[s][d]
    __shared__ short Vt [64 * LDSTR];  // V^T[dv][s]
    __shared__ short Ps [64 * LDSTR];  // masked scores P[t][s] (bf16)
    __shared__ float zprev[64];
    __shared__ float rden[64];

    const int tid = threadIdx.x;
    const int w = tid >> 6, lane = tid & 63;
    const int lm = lane & 15, quad = lane >> 4;
    const size_t coff = ((size_t)bh * T_SEQ + c * CS) * HD;
    const float* Sp = KV + ((size_t)bh * NCHUNK + c) * 4096;

    #pragma unroll
    for (int j = 0; j < 2; ++j) {
        const int u  = j * 256 + tid;
        const int e0 = u * 8;
        const int r = e0 >> 6, cc = e0 & 63;
        *reinterpret_cast<short8*>(&Qs [r * LDSTR + cc]) =
            *reinterpret_cast<const short8*>(Qf + coff + e0);
        *reinterpret_cast<short8*>(&Ksn[r * LDSTR + cc]) =
            *reinterpret_cast<const short8*>(Kf + coff + e0);
        short8 vu = *reinterpret_cast<const short8*>(Vf + coff + e0);
        #pragma unroll
        for (int i = 0; i < 8; ++i) Vt[(cc + i) * LDSTR + r] = vu[i];
    }
    if (tid < 64) zprev[tid] = ksum[((size_t)bh * NCHUNK + c) * 64 + tid];
    __syncthreads();

    // ---- P = Q K^T (wave w owns t-rows [w*16, w*16+16)) ----
    floatx4 pacc[4];
    const floatx4 zero = {0.f, 0.f, 0.f, 0.f};
    #pragma unroll
    for (int nt = 0; nt < 4; ++nt) pacc[nt] = zero;
    #pragma unroll
    for (int ks = 0; ks < 2; ++ks) {
        short8 aq = *reinterpret_cast<const short8*>(
            &Qs[(w * 16 + lm) * LDSTR + ks * 32 + quad * 8]);
        #pragma unroll
        for (int nt = 0; nt < 4; ++nt) {
            short8 bk = *reinterpret_cast<const short8*>(
                &Ksn[(nt * 16 + lm) * LDSTR + ks * 32 + quad * 8]);
            pacc[nt] = __builtin_amdgcn_mfma_f32_16x16x32_bf16(aq, bk, pacc[nt], 0, 0, 0);
        }
    }
    // mask + store P to LDS as bf16 (C-layout -> A-layout round-trip)
    #pragma unroll
    for (int nt = 0; nt < 4; ++nt)
        #pragma unroll
        for (int r = 0; r < 4; ++r) {
            const int t = w * 16 + quad * 4 + r;
            const int s = nt * 16 + lm;
            Ps[t * LDSTR + s] = f2bs((s <= t) ? pacc[nt][r] : 0.f);
        }

    // ---- Q @ S_prev (scalar fp32; S state stays full precision) ----
    floatx4 oacc[4];
    #pragma unroll
    for (int nt = 0; nt < 4; ++nt) oacc[nt] = zero;
    for (int d = 0; d < 64; ++d) {
        float qv[4];
        #pragma unroll
        for (int r = 0; r < 4; ++r)
            qv[r] = bs2f(Qs[(w * 16 + quad * 4 + r) * LDSTR + d]);
        #pragma unroll
        for (int nt = 0; nt < 4; ++nt) {
            const float sv = Sp[d * 64 + nt * 16 + lm];
            #pragma unroll
            for (int r = 0; r < 4; ++r) oacc[nt][r] += qv[r] * sv;
        }
    }
    __syncthreads();   // Ps complete

    if (tid < 64) {
        float rs = 0.f;
        #pragma unroll 8
        for (int s = 0; s < 64; ++s) rs += bs2f(Ps[tid * LDSTR + s]);
        float dz = 0.f;
        #pragma unroll 8
        for (int d = 0; d < 64; ++d) dz += bs2f(Qs[tid * LDSTR + d]) * zprev[d];
        rden[tid] = 1.f / (rs + dz + 1e-6f);
    }

    // ---- O += P V ----
    #pragma unroll
    for (int ks = 0; ks < 2; ++ks) {
        short8 ap = *reinterpret_cast<const short8*>(
            &Ps[(w * 16 + lm) * LDSTR + ks * 32 + quad * 8]);
        #pragma unroll
        for (int nt = 0; nt < 4; ++nt) {
            short8 bv = *reinterpret_cast<const short8*>(
                &Vt[(nt * 16 + lm) * LDSTR + ks * 32 + quad * 8]);
            oacc[nt] = __builtin_amdgcn_mfma_f32_16x16x32_bf16(ap, bv, oacc[nt], 0, 0, 0);
        }
    }
    __syncthreads();   // rden ready

    #pragma unroll
    for (int nt = 0; nt < 4; ++nt)
        #pragma unroll
        for (int r = 0; r < 4; ++r) {
            const int t  = w * 16 + quad * 4 + r;
            const int dv = nt * 16 + lm;
            const int tg = c * CS + t;
            Of[((size_t)(b * T_SEQ + tg)) * EMB + h * HD + dv] =
                __float2bfloat16(oacc[nt][r] * rden[t]);
        }
}

// ---------------------------------------------------------------------------
// Kernel 5: output projection via MFMA (validated round 4).
// ---------------------------------------------------------------------------
template <typename T>
__global__ __launch_bounds__(256) void out_proj_mfma(
    const int* __restrict__ flag,
    const bf16* __restrict__ A, const T* __restrict__ Wo,
    const T* __restrict__ bo, T* __restrict__ out)
{
    if (*flag != ModeOf<T>::v) return;

    const int mbase = blockIdx.x * 128;
    const int nbase = blockIdx.y * 128;

    __shared__ short As[128 * LDSTR];
    __shared__ short Bs[128 * LDSTR];

    const int tid  = threadIdx.x;
    const int wave = tid >> 6, lane = tid & 63;
    const int wm = wave >> 1, wn = wave & 1;
    const int lm = lane & 15, quad = lane >> 4;

    floatx4 acc[4][4];
    const floatx4 zero = {0.f, 0.f, 0.f, 0.f};
    #pragma unroll
    for (int mt = 0; mt < 4; ++mt)
        #pragma unroll
        for (int nt = 0; nt < 4; ++nt) acc[mt][nt] = zero;

    for (int kt = 0; kt < EMB; kt += 64) {
        #pragma unroll
        for (int i = 0; i < 4; ++i) {
            const int c = tid + i * 256;
            const int row = c >> 3, k8 = (c & 7) * 8;
            stage8(A  + (size_t)(mbase + row) * EMB + kt + k8, &As[row * LDSTR + k8]);
            stage8(Wo + (size_t)(nbase + row) * EMB + kt + k8, &Bs[row * LDSTR + k8]);
        }
        __syncthreads();
        #pragma unroll
        for (int ks = 0; ks < 2; ++ks) {
            short8 af[4], bfr[4];
            #pragma unroll
            for (int mt = 0; mt < 4; ++mt)
                af[mt] = *reinterpret_cast<const short8*>(
                    &As[(wm * 64 + mt * 16 + lm) * LDSTR + ks * 32 + quad * 8]);
            #pragma unroll
            for (int nt = 0; nt < 4; ++nt)
                bfr[nt] = *reinterpret_cast<const short8*>(
                    &Bs[(wn * 64 + nt * 16 + lm) * LDSTR + ks * 32 + quad * 8]);
            #pragma unroll
            for (int mt = 0; mt < 4; ++mt)
                #pragma unroll
                for (int nt = 0; nt < 4; ++nt)
                    acc[mt][nt] = __builtin_amdgcn_mfma_f32_16x16x32_bf16(
                        af[mt], bfr[nt], acc[mt][nt], 0, 0, 0);
        }
        __syncthreads();
    }

    #pragma unroll
    for (int nt = 0; nt < 4; ++nt) {
        const int col = nbase + wn * 64 + nt * 16 + lm;
        const float bv_ = load_elem(bo, col);
        #pragma unroll
        for (int mt = 0; mt < 4; ++mt)
            #pragma unroll
            for (int r = 0; r < 4; ++r) {
                const int row = mbase + wm * 64 + mt * 16 + quad * 4 + r;
                store_elem(out, (size_t)row * EMB + col, acc[mt][nt][r] + bv_);
            }
    }
}

// ---------------------------------------------------------------------------
extern "C" void kernel_launch(void* const* d_in, const int* in_sizes, int n_in,
                              void* d_out, int out_size, void* d_ws, size_t ws_size,
                              hipStream_t stream)
{
    // workspace layout (48.25 MB + 64 B — validated):
    int*  flag = (int*)d_ws;
    bf16* Qf = (bf16*)((char*)d_ws + 64);
    bf16* Kf = Qf + 4194304;
    bf16* Vf = Kf + 4194304;
    float* KV = (float*)(Vf + 4194304);
    float* ks = KV + 4194304;
    bf16* Of = (bf16*)(ks + 65536);

    detect_dtype<<<1, 64, 0, stream>>>((const unsigned short*)d_in[0], flag);

    qkv_mfma<bf16><<<dim3(64, 12), 256, 0, stream>>>(flag,
        (const bf16*)d_in[0],
        (const bf16*)d_in[1], (const bf16*)d_in[2],
        (const bf16*)d_in[3], (const bf16*)d_in[4],
        (const bf16*)d_in[5], (const bf16*)d_in[6],
        Qf, Kf, Vf);
    qkv_mfma<float><<<dim3(64, 12), 256, 0, stream>>>(flag,
        (const float*)d_in[0],
        (const float*)d_in[1], (const float*)d_in[2],
        (const float*)d_in[3], (const float*)d_in[4],
        (const float*)d_in[5], (const float*)d_in[6],
        Qf, Kf, Vf);

    chunk_kv<<<dim3(BHEADS * NCHUNK), 256, 0, stream>>>(Kf, Vf, KV, ks);
    prefix_kv<<<dim3(BHEADS * 16), 256, 0, stream>>>(KV, ks);
    attn_mfma<<<dim3(BHEADS * NCHUNK), 256, 0, stream>>>(Qf, Kf, Vf, KV, ks, Of);

    out_proj_mfma<bf16><<<dim3(64, 4), 256, 0, stream>>>(flag,
        Of, (const bf16*)d_in[7], (const bf16*)d_in[8], (bf16*)d_out);
    out_proj_mfma<float><<<dim3(64, 4), 256, 0, stream>>>(flag,
        Of, (const float*)d_in[7], (const float*)d_in[8], (float*)d_out);
}

// Round 6
// 167.157 us; speedup vs baseline: 2.9962x; 1.0278x over previous
//
#include <hip/hip_runtime.h>
#include <hip/hip_bf16.h>

// Problem constants: B=2, T=4096, E=512, H=8, D=64
#define T_SEQ 4096
#define EMB   512
#define NH    8
#define HD    64
#define BATCH 2
#define M_ROWS (BATCH * T_SEQ)   // 8192
#define NCHUNK 64                // T / CS
#define CS     64                // chunk size
#define BHEADS (BATCH * NH)      // 16

using bf16 = __hip_bfloat16;
typedef __attribute__((ext_vector_type(8))) short short8;   // 8 bf16 = 4 VGPR
typedef __attribute__((ext_vector_type(4))) float floatx4;  // MFMA acc

__device__ __forceinline__ float bs2f(short s) {
    return __uint_as_float(((unsigned)(unsigned short)s) << 16);
}
__device__ __forceinline__ short f2bs(float f) {
    bf16 h = __float2bfloat16(f);
    return *reinterpret_cast<short*>(&h);
}
__device__ __forceinline__ float load_elem(const bf16* p, size_t i) {
    return __bfloat162float(p[i]);
}
__device__ __forceinline__ void store_elem(bf16* p, size_t i, float v) {
    p[i] = __float2bfloat16(v);
}
__device__ __forceinline__ void store_elem(float* p, size_t i, float v) {
    p[i] = v;
}
// convert 8 consecutive elems (any dtype) -> bf16, 16B write
__device__ __forceinline__ void stage8(const bf16* g, short* l) {
    *reinterpret_cast<short8*>(l) = *reinterpret_cast<const short8*>(g);
}
__device__ __forceinline__ void stage8(const float* g, short* l) {
    float4 a = *reinterpret_cast<const float4*>(g);
    float4 b = *reinterpret_cast<const float4*>(g + 4);
    short8 v;
    v[0] = f2bs(a.x); v[1] = f2bs(a.y); v[2] = f2bs(a.z); v[3] = f2bs(a.w);
    v[4] = f2bs(b.x); v[5] = f2bs(b.y); v[6] = f2bs(b.z); v[7] = f2bs(b.w);
    *reinterpret_cast<short8*>(l) = v;
}
template <typename T> struct ModeOf { static constexpr int v = 0; };  // bf16
template <> struct ModeOf<float>    { static constexpr int v = 1; };  // fp32

// async global->LDS: each lane copies 16B to (wave-uniform base) + lane*16
__device__ __forceinline__ void gload_lds16(const short* g, short* l) {
    __builtin_amdgcn_global_load_lds(
        (const __attribute__((address_space(1))) void*)g,
        (__attribute__((address_space(3))) void*)l, 16, 0, 0);
}

#define LDSTR 72   // padded LDS row stride (shorts) for transposed tiles

// ---------------------------------------------------------------------------
// Kernel 0: dtype detector — contiguous 8KB probe (fast).  If x is fp32, the
// low 16-bit halves of its words viewed as bf16 have uniform exponents ->
// some are huge/NaN.  Real bf16 activations never exceed ~6.
// ---------------------------------------------------------------------------
__global__ void detect_dtype(const unsigned short* __restrict__ xraw,
                             int* __restrict__ flag)
{
    __shared__ int bad_s;
    const int tid = threadIdx.x;   // 256
    if (tid == 0) bad_s = 0;
    __syncthreads();
    bool bad = false;
    #pragma unroll
    for (int i = 0; i < 2; ++i) {
        uint4 u = reinterpret_cast<const uint4*>(xraw)[tid + i * 256];
        const unsigned w[4] = {u.x, u.y, u.z, u.w};
        #pragma unroll
        for (int k = 0; k < 4; ++k) {
            const float f = __uint_as_float(w[k] << 16);   // even short
            if (!(fabsf(f) <= 1e9f)) bad = true;
        }
    }
    if (bad) atomicOr(&bad_s, 1);
    __syncthreads();
    if (tid == 0) *flag = bad_s ? 1 : 0;
}

// ---------------------------------------------------------------------------
// Kernel 1: convert x, Wq/Wk/Wv/Wo, biases -> bf16 workspace (dual-variant).
// Segments in 8-elem chunks: x 524288 | W 4x32768 | b 4x64.  Grid 2561x256.
// ---------------------------------------------------------------------------
template <typename T>
__global__ __launch_bounds__(256) void convert_all(
    const int* __restrict__ flag,
    const T* __restrict__ x,
    const T* __restrict__ Wq, const T* __restrict__ bq,
    const T* __restrict__ Wk, const T* __restrict__ bk,
    const T* __restrict__ Wv, const T* __restrict__ bv,
    const T* __restrict__ Wo, const T* __restrict__ bo,
    short* __restrict__ xb, short* __restrict__ Wb, short* __restrict__ bb)
{
    if (*flag != ModeOf<T>::v) return;
    const int c = blockIdx.x * 256 + threadIdx.x;
    if (c < 524288) {
        stage8(x + (size_t)c * 8, xb + (size_t)c * 8);
    } else if (c < 655360) {
        const int c2 = c - 524288;
        const int w = c2 >> 15;             // 0..3
        const int off = (c2 & 32767) * 8;
        const T* src = (w == 0) ? Wq : (w == 1) ? Wk : (w == 2) ? Wv : Wo;
        stage8(src + off, Wb + w * 262144 + off);
    } else {
        const int c3 = c - 655360;          // 0..255
        const int bsel = c3 >> 6;
        const int off = (c3 & 63) * 8;
        const T* src = (bsel == 0) ? bq : (bsel == 1) ? bk : (bsel == 2) ? bv : bo;
        stage8(src + off, bb + bsel * 512 + off);
    }
}

// ---------------------------------------------------------------------------
// Kernel 2: fused QKV projection, bf16 inputs, global_load_lds staging.
// 128x128 tile, BK=64, packed LDS stride 64 (m97 structure).  Grid (64,12);
// blockIdx.y>>2 selects Q/K/V.  elu+1 on Q,K.  Output (B,H,T,D) bf16.
// ---------------------------------------------------------------------------
__global__ __launch_bounds__(256) void qkv_gemm_dl(
    const short* __restrict__ xb, const short* __restrict__ Wb,
    const short* __restrict__ bb,
    bf16* __restrict__ Qf, bf16* __restrict__ Kf, bf16* __restrict__ Vf)
{
    const int mtile = blockIdx.x;            // 0..63
    const int ntile = blockIdx.y;            // 0..11
    const int which = ntile >> 2;
    const short* W = Wb + (size_t)which * 262144;
    const bf16* bias = (const bf16*)(bb + which * 512);
    bf16* outp = (which == 0) ? Qf : ((which == 1) ? Kf : Vf);
    const int nbase = (ntile & 3) * 128;
    const int mbase = mtile * 128;

    __shared__ short As[128 * 64];   // packed: row stride 64 shorts (128 B)
    __shared__ short Bs[128 * 64];

    const int tid  = threadIdx.x;
    const int wave = tid >> 6, lane = tid & 63;
    const int wm = wave >> 1, wn = wave & 1;
    const int lm = lane & 15, quad = lane >> 4;
    const int srow = lane >> 3;           // 0..7 within issue
    const int scol = (lane & 7) * 8;      // 0,8,..,56

    floatx4 acc[4][4];
    const floatx4 zero = {0.f, 0.f, 0.f, 0.f};
    #pragma unroll
    for (int mt = 0; mt < 4; ++mt)
        #pragma unroll
        for (int nt = 0; nt < 4; ++nt) acc[mt][nt] = zero;

    for (int kt = 0; kt < EMB; kt += 64) {
        #pragma unroll
        for (int j = 0; j < 4; ++j) {
            const int issue = wave * 4 + j;          // 0..15, 8 rows each
            const int row = issue * 8 + srow;
            gload_lds16(xb + (size_t)(mbase + row) * EMB + kt + scol,
                        &As[issue * 512]);
            gload_lds16(W  + (size_t)(nbase + row) * EMB + kt + scol,
                        &Bs[issue * 512]);
        }
        __syncthreads();
        #pragma unroll
        for (int ks = 0; ks < 2; ++ks) {
            short8 af[4], bfr[4];
            #pragma unroll
            for (int mt = 0; mt < 4; ++mt)
                af[mt] = *reinterpret_cast<const short8*>(
                    &As[(wm * 64 + mt * 16 + lm) * 64 + ks * 32 + quad * 8]);
            #pragma unroll
            for (int nt = 0; nt < 4; ++nt)
                bfr[nt] = *reinterpret_cast<const short8*>(
                    &Bs[(wn * 64 + nt * 16 + lm) * 64 + ks * 32 + quad * 8]);
            #pragma unroll
            for (int mt = 0; mt < 4; ++mt)
                #pragma unroll
                for (int nt = 0; nt < 4; ++nt)
                    acc[mt][nt] = __builtin_amdgcn_mfma_f32_16x16x32_bf16(
                        af[mt], bfr[nt], acc[mt][nt], 0, 0, 0);
        }
        __syncthreads();
    }

    #pragma unroll
    for (int nt = 0; nt < 4; ++nt) {
        const int col = nbase + wn * 64 + nt * 16 + lm;   // 0..511
        const float bv_ = load_elem(bias, col & 511);
        const int h = col >> 6, d = col & 63;
        #pragma unroll
        for (int mt = 0; mt < 4; ++mt)
            #pragma unroll
            for (int r = 0; r < 4; ++r) {
                const int row = mbase + wm * 64 + mt * 16 + quad * 4 + r;
                const int b = row >> 12, t = row & (T_SEQ - 1);
                float v = acc[mt][nt][r] + bv_;
                if (which != 2) v = (v > 0.f) ? (v + 1.f) : __expf(v);  // elu+1
                outp[(((size_t)(b * NH + h)) * T_SEQ + t) * HD + d] = __float2bfloat16(v);
            }
    }
}

// ---------------------------------------------------------------------------
// Kernel 3: per-chunk K^T V via MFMA + k column sums (validated round 5).
// ---------------------------------------------------------------------------
__global__ __launch_bounds__(256) void chunk_kv(
    const bf16* __restrict__ Kf, const bf16* __restrict__ Vf,
    float* __restrict__ KV, float* __restrict__ ksum)
{
    const int bh = blockIdx.x >> 6;
    const int c  = blockIdx.x & 63;
    __shared__ short Kt[64 * LDSTR];   // Kt[d][s]
    __shared__ short Vt[64 * LDSTR];   // Vt[d][s]
    const int tid = threadIdx.x;
    const bf16* kp = Kf + ((size_t)bh * T_SEQ + c * CS) * HD;
    const bf16* vp = Vf + ((size_t)bh * T_SEQ + c * CS) * HD;

    #pragma unroll
    for (int j = 0; j < 2; ++j) {
        const int u = j * 256 + tid;
        const int e0 = u * 8;
        const int s = e0 >> 6, d0 = e0 & 63;
        short8 ku = *reinterpret_cast<const short8*>(kp + e0);
        short8 vu = *reinterpret_cast<const short8*>(vp + e0);
        #pragma unroll
        for (int i = 0; i < 8; ++i) {
            Kt[(d0 + i) * LDSTR + s] = ku[i];
            Vt[(d0 + i) * LDSTR + s] = vu[i];
        }
    }
    __syncthreads();

    const int w = tid >> 6, lane = tid & 63;
    const int lm = lane & 15, quad = lane >> 4;

    floatx4 acc[4];
    const floatx4 zero = {0.f, 0.f, 0.f, 0.f};
    #pragma unroll
    for (int nt = 0; nt < 4; ++nt) acc[nt] = zero;

    #pragma unroll
    for (int ks = 0; ks < 2; ++ks) {
        short8 ak = *reinterpret_cast<const short8*>(
            &Kt[(w * 16 + lm) * LDSTR + ks * 32 + quad * 8]);
        #pragma unroll
        for (int nt = 0; nt < 4; ++nt) {
            short8 bv = *reinterpret_cast<const short8*>(
                &Vt[(nt * 16 + lm) * LDSTR + ks * 32 + quad * 8]);
            acc[nt] = __builtin_amdgcn_mfma_f32_16x16x32_bf16(ak, bv, acc[nt], 0, 0, 0);
        }
    }

    float* kvout = KV + ((size_t)bh * NCHUNK + c) * 4096;
    #pragma unroll
    for (int nt = 0; nt < 4; ++nt)
        #pragma unroll
        for (int r = 0; r < 4; ++r) {
            const int dk = w * 16 + quad * 4 + r;
            const int dv = nt * 16 + lm;
            kvout[dk * 64 + dv] = acc[nt][r];
        }

    if (tid < 64) {
        float s = 0.f;
        #pragma unroll 8
        for (int t = 0; t < 64; ++t) s += bs2f(Kt[tid * LDSTR + t]);
        ksum[((size_t)bh * NCHUNK + c) * 64 + tid] = s;
    }
}

// ---------------------------------------------------------------------------
// Kernel 4: exclusive prefix over chunks — element-parallel (validated r5).
// ---------------------------------------------------------------------------
__global__ __launch_bounds__(256) void prefix_kv(
    float* __restrict__ KV, float* __restrict__ ksum)
{
    const int bh   = blockIdx.x >> 4;
    const int part = blockIdx.x & 15;
    const int tid  = threadIdx.x;
    const int e    = part * 256 + tid;
    float* base = KV + (size_t)bh * NCHUNK * 4096 + e;

    float s = 0.f;
    #pragma unroll
    for (int cb = 0; cb < 4; ++cb) {
        float v[16];
        #pragma unroll
        for (int i = 0; i < 16; ++i) v[i] = base[(size_t)(cb * 16 + i) * 4096];
        #pragma unroll
        for (int i = 0; i < 16; ++i) {
            const float tmp = v[i];
            base[(size_t)(cb * 16 + i) * 4096] = s;
            s += tmp;
        }
    }

    if (part == 0 && tid < 64) {
        float* zb = ksum + (size_t)bh * NCHUNK * 64 + tid;
        float z = 0.f;
        #pragma unroll
        for (int cb = 0; cb < 4; ++cb) {
            float v[16];
            #pragma unroll
            for (int i = 0; i < 16; ++i) v[i] = zb[(size_t)(cb * 16 + i) * 64];
            #pragma unroll
            for (int i = 0; i < 16; ++i) {
                const float tmp = v[i];
                zb[(size_t)(cb * 16 + i) * 64] = z;
                z += tmp;
            }
        }
    }
}

// ---------------------------------------------------------------------------
// Kernel 5: per-chunk attention, all-MFMA.
// P = mask(Q K^T); O = P V + Q S_prev (S_prev bf16-staged, transposed);
// den = rowsum(P) + q.z_prev + eps.  1024 blocks (bh,c).
// ---------------------------------------------------------------------------
__global__ __launch_bounds__(256) void attn_mfma(
    const bf16* __restrict__ Qf, const bf16* __restrict__ Kf,
    const bf16* __restrict__ Vf, const float* __restrict__ KV,
    const float* __restrict__ ksum, bf16* __restrict__ Of)
{
    const int bh = blockIdx.x >> 6;
    const int c  = blockIdx.x & 63;
    const int b  = bh >> 3, h = bh & 7;

    __shared__ short Qs [64 * LDSTR];  // Q[t][d]
    __shared__ short Ksn[64 * LDSTR];  // K[s][d]
    __shared__ short Vt [64 * LDSTR];  // V^T[dv][s]
    __shared__ short Ps [64 * LDSTR];  // masked scores P[t][s]
    __shared__ short St [64 * LDSTR];  // S_prev^T[dv][d] (bf16)
    __shared__ float zprev[64];
    __shared__ float rden[64];

    const int tid = threadIdx.x;
    const int w = tid >> 6, lane = tid & 63;
    const int lm = lane & 15, quad = lane >> 4;
    const size_t coff = ((size_t)bh * T_SEQ + c * CS) * HD;
    const float* Sp = KV + ((size_t)bh * NCHUNK + c) * 4096;

    #pragma unroll
    for (int j = 0; j < 2; ++j) {
        const int u  = j * 256 + tid;
        const int e0 = u * 8;
        const int r = e0 >> 6, cc = e0 & 63;
        *reinterpret_cast<short8*>(&Qs [r * LDSTR + cc]) =
            *reinterpret_cast<const short8*>(Qf + coff + e0);
        *reinterpret_cast<short8*>(&Ksn[r * LDSTR + cc]) =
            *reinterpret_cast<const short8*>(Kf + coff + e0);
        short8 vu = *reinterpret_cast<const short8*>(Vf + coff + e0);
        #pragma unroll
        for (int i = 0; i < 8; ++i) Vt[(cc + i) * LDSTR + r] = vu[i];
    }
    // S_prev (fp32, [dk][dv]) -> St[dv][dk] bf16
    #pragma unroll
    for (int j = 0; j < 4; ++j) {
        const int u = j * 256 + tid;           // 0..1023 float4
        const float4 s4 = reinterpret_cast<const float4*>(Sp)[u];
        const int d = u >> 4;
        const int dv0 = (u & 15) * 4;
        St[(dv0 + 0) * LDSTR + d] = f2bs(s4.x);
        St[(dv0 + 1) * LDSTR + d] = f2bs(s4.y);
        St[(dv0 + 2) * LDSTR + d] = f2bs(s4.z);
        St[(dv0 + 3) * LDSTR + d] = f2bs(s4.w);
    }
    if (tid < 64) zprev[tid] = ksum[((size_t)bh * NCHUNK + c) * 64 + tid];
    __syncthreads();

    const floatx4 zero = {0.f, 0.f, 0.f, 0.f};
    // A-fragments of Q (rows t = w*16 + ...), shared by QK^T and Q@S
    short8 aq[2];
    #pragma unroll
    for (int ks = 0; ks < 2; ++ks)
        aq[ks] = *reinterpret_cast<const short8*>(
            &Qs[(w * 16 + lm) * LDSTR + ks * 32 + quad * 8]);

    // ---- P = Q K^T ----
    floatx4 pacc[4];
    #pragma unroll
    for (int nt = 0; nt < 4; ++nt) pacc[nt] = zero;
    #pragma unroll
    for (int ks = 0; ks < 2; ++ks)
        #pragma unroll
        for (int nt = 0; nt < 4; ++nt) {
            short8 bk = *reinterpret_cast<const short8*>(
                &Ksn[(nt * 16 + lm) * LDSTR + ks * 32 + quad * 8]);
            pacc[nt] = __builtin_amdgcn_mfma_f32_16x16x32_bf16(aq[ks], bk, pacc[nt], 0, 0, 0);
        }
    #pragma unroll
    for (int nt = 0; nt < 4; ++nt)
        #pragma unroll
        for (int r = 0; r < 4; ++r) {
            const int t = w * 16 + quad * 4 + r;
            const int s = nt * 16 + lm;
            Ps[t * LDSTR + s] = f2bs((s <= t) ? pacc[nt][r] : 0.f);
        }

    // ---- O = Q @ S_prev (MFMA) ----
    floatx4 oacc[4];
    #pragma unroll
    for (int nt = 0; nt < 4; ++nt) oacc[nt] = zero;
    #pragma unroll
    for (int ks = 0; ks < 2; ++ks)
        #pragma unroll
        for (int nt = 0; nt < 4; ++nt) {
            short8 bs = *reinterpret_cast<const short8*>(
                &St[(nt * 16 + lm) * LDSTR + ks * 32 + quad * 8]);
            oacc[nt] = __builtin_amdgcn_mfma_f32_16x16x32_bf16(aq[ks], bs, oacc[nt], 0, 0, 0);
        }
    __syncthreads();   // Ps complete

    if (tid < 64) {
        float rs = 0.f;
        #pragma unroll 8
        for (int s = 0; s < 64; ++s) rs += bs2f(Ps[tid * LDSTR + s]);
        float dz = 0.f;
        #pragma unroll 8
        for (int d = 0; d < 64; ++d) dz += bs2f(Qs[tid * LDSTR + d]) * zprev[d];
        rden[tid] = 1.f / (rs + dz + 1e-6f);
    }

    // ---- O += P V ----
    #pragma unroll
    for (int ks = 0; ks < 2; ++ks) {
        short8 ap = *reinterpret_cast<const short8*>(
            &Ps[(w * 16 + lm) * LDSTR + ks * 32 + quad * 8]);
        #pragma unroll
        for (int nt = 0; nt < 4; ++nt) {
            short8 bv = *reinterpret_cast<const short8*>(
                &Vt[(nt * 16 + lm) * LDSTR + ks * 32 + quad * 8]);
            oacc[nt] = __builtin_amdgcn_mfma_f32_16x16x32_bf16(ap, bv, oacc[nt], 0, 0, 0);
        }
    }
    __syncthreads();   // rden ready

    #pragma unroll
    for (int nt = 0; nt < 4; ++nt)
        #pragma unroll
        for (int r = 0; r < 4; ++r) {
            const int t  = w * 16 + quad * 4 + r;
            const int dv = nt * 16 + lm;
            const int tg = c * CS + t;
            Of[((size_t)(b * T_SEQ + tg)) * EMB + h * HD + dv] =
                __float2bfloat16(oacc[nt][r] * rden[t]);
        }
}

// ---------------------------------------------------------------------------
// Kernel 6: output projection, global_load_lds, dual-variant (store dtype).
// out = Of @ Wo^T + bo.  Grid (64, 4).
// ---------------------------------------------------------------------------
template <typename T>
__global__ __launch_bounds__(256) void out_proj_dl(
    const int* __restrict__ flag,
    const short* __restrict__ A, const short* __restrict__ Wb,
    const short* __restrict__ bb, T* __restrict__ out)
{
    if (*flag != ModeOf<T>::v) return;

    const int mbase = blockIdx.x * 128;
    const int nbase = blockIdx.y * 128;
    const short* W = Wb + (size_t)3 * 262144;
    const bf16* bias = (const bf16*)(bb + 3 * 512);

    __shared__ short As[128 * 64];
    __shared__ short Bs[128 * 64];

    const int tid  = threadIdx.x;
    const int wave = tid >> 6, lane = tid & 63;
    const int wm = wave >> 1, wn = wave & 1;
    const int lm = lane & 15, quad = lane >> 4;
    const int srow = lane >> 3;
    const int scol = (lane & 7) * 8;

    floatx4 acc[4][4];
    const floatx4 zero = {0.f, 0.f, 0.f, 0.f};
    #pragma unroll
    for (int mt = 0; mt < 4; ++mt)
        #pragma unroll
        for (int nt = 0; nt < 4; ++nt) acc[mt][nt] = zero;

    for (int kt = 0; kt < EMB; kt += 64) {
        #pragma unroll
        for (int j = 0; j < 4; ++j) {
            const int issue = wave * 4 + j;
            const int row = issue * 8 + srow;
            gload_lds16(A + (size_t)(mbase + row) * EMB + kt + scol,
                        &As[issue * 512]);
            gload_lds16(W + (size_t)(nbase + row) * EMB + kt + scol,
                        &Bs[issue * 512]);
        }
        __syncthreads();
        #pragma unroll
        for (int ks = 0; ks < 2; ++ks) {
            short8 af[4], bfr[4];
            #pragma unroll
            for (int mt = 0; mt < 4; ++mt)
                af[mt] = *reinterpret_cast<const short8*>(
                    &As[(wm * 64 + mt * 16 + lm) * 64 + ks * 32 + quad * 8]);
            #pragma unroll
            for (int nt = 0; nt < 4; ++nt)
                bfr[nt] = *reinterpret_cast<const short8*>(
                    &Bs[(wn * 64 + nt * 16 + lm) * 64 + ks * 32 + quad * 8]);
            #pragma unroll
            for (int mt = 0; mt < 4; ++mt)
                #pragma unroll
                for (int nt = 0; nt < 4; ++nt)
                    acc[mt][nt] = __builtin_amdgcn_mfma_f32_16x16x32_bf16(
                        af[mt], bfr[nt], acc[mt][nt], 0, 0, 0);
        }
        __syncthreads();
    }

    #pragma unroll
    for (int nt = 0; nt < 4; ++nt) {
        const int col = nbase + wn * 64 + nt * 16 + lm;
        const float bv_ = load_elem(bias, col);
        #pragma unroll
        for (int mt = 0; mt < 4; ++mt)
            #pragma unroll
            for (int r = 0; r < 4; ++r) {
                const int row = mbase + wm * 64 + mt * 16 + quad * 4 + r;
                store_elem(out, (size_t)row * EMB + col, acc[mt][nt][r] + bv_);
            }
    }
}

// ---------------------------------------------------------------------------
extern "C" void kernel_launch(void* const* d_in, const int* in_sizes, int n_in,
                              void* d_out, int out_size, void* d_ws, size_t ws_size,
                              hipStream_t stream)
{
    // workspace (~50.3 MB):
    //   flag   : 64 B
    //   Qf/Kf/Vf : bf16 4,194,304 each                (24 MB)
    //   union  : [ KV fp32 4,194,304 | xb bf16 4,194,304 ]  (16 MB)
    //            xb live: convert->qkv; KV live: chunk_kv->attn (disjoint)
    //   ksum   : fp32 65,536                           (0.25 MB)
    //   Of     : bf16 4,194,304                        (8 MB)
    //   Wb     : bf16 4x262,144                        (2 MB)
    //   bb     : bf16 4x512                            (4 KB)
    int*  flag = (int*)d_ws;
    bf16* Qf = (bf16*)((char*)d_ws + 64);
    bf16* Kf = Qf + 4194304;
    bf16* Vf = Kf + 4194304;
    float* KV = (float*)(Vf + 4194304);
    short* xb = (short*)KV;                 // aliased (disjoint lifetime)
    float* ks = KV + 4194304;
    bf16* Of = (bf16*)(ks + 65536);
    short* Wb = (short*)(Of + 4194304);
    short* bb = Wb + 1048576;

    detect_dtype<<<1, 256, 0, stream>>>((const unsigned short*)d_in[0], flag);

    convert_all<bf16><<<dim3(2561), 256, 0, stream>>>(flag,
        (const bf16*)d_in[0],
        (const bf16*)d_in[1], (const bf16*)d_in[2],
        (const bf16*)d_in[3], (const bf16*)d_in[4],
        (const bf16*)d_in[5], (const bf16*)d_in[6],
        (const bf16*)d_in[7], (const bf16*)d_in[8],
        xb, Wb, bb);
    convert_all<float><<<dim3(2561), 256, 0, stream>>>(flag,
        (const float*)d_in[0],
        (const float*)d_in[1], (const float*)d_in[2],
        (const float*)d_in[3], (const float*)d_in[4],
        (const float*)d_in[5], (const float*)d_in[6],
        (const float*)d_in[7], (const float*)d_in[8],
        xb, Wb, bb);

    qkv_gemm_dl<<<dim3(64, 12), 256, 0, stream>>>(xb, Wb, bb, Qf, Kf, Vf);
    chunk_kv<<<dim3(BHEADS * NCHUNK), 256, 0, stream>>>(Kf, Vf, KV, ks);
    prefix_kv<<<dim3(BHEADS * 16), 256, 0, stream>>>(KV, ks);
    attn_mfma<<<dim3(BHEADS * NCHUNK), 256, 0, stream>>>(Qf, Kf, Vf, KV, ks, Of);

    out_proj_dl<bf16><<<dim3(64, 4), 256, 0, stream>>>(flag,
        (const short*)Of, Wb, bb, (bf16*)d_out);
    out_proj_dl<float><<<dim3(64, 4), 256, 0, stream>>>(flag,
        (const short*)Of, Wb, bb, (float*)d_out);
}

// Round 7
// 161.648 us; speedup vs baseline: 3.0983x; 1.0341x over previous
//
#include <hip/hip_runtime.h>
#include <hip/hip_bf16.h>

// Problem constants: B=2, T=4096, E=512, H=8, D=64
#define T_SEQ 4096
#define EMB   512
#define NH    8
#define HD    64
#define BATCH 2
#define M_ROWS (BATCH * T_SEQ)   // 8192
#define NCHUNK 64                // T / CS
#define CS     64                // chunk size
#define BHEADS (BATCH * NH)      // 16

using bf16 = __hip_bfloat16;
typedef __attribute__((ext_vector_type(8))) short short8;   // 8 bf16 = 4 VGPR
typedef __attribute__((ext_vector_type(4))) short short4v;  // 8B LDS store
typedef __attribute__((ext_vector_type(4))) float floatx4;  // MFMA acc

__device__ __forceinline__ float bs2f(short s) {
    return __uint_as_float(((unsigned)(unsigned short)s) << 16);
}
__device__ __forceinline__ short f2bs(float f) {
    bf16 h = __float2bfloat16(f);
    return *reinterpret_cast<short*>(&h);
}
__device__ __forceinline__ float load_elem(const bf16* p, size_t i) {
    return __bfloat162float(p[i]);
}
// convert 8 consecutive elems (any dtype) -> bf16, 16B write
__device__ __forceinline__ void stage8(const bf16* g, short* l) {
    *reinterpret_cast<short8*>(l) = *reinterpret_cast<const short8*>(g);
}
__device__ __forceinline__ void stage8(const float* g, short* l) {
    float4 a = *reinterpret_cast<const float4*>(g);
    float4 b = *reinterpret_cast<const float4*>(g + 4);
    short8 v;
    v[0] = f2bs(a.x); v[1] = f2bs(a.y); v[2] = f2bs(a.z); v[3] = f2bs(a.w);
    v[4] = f2bs(b.x); v[5] = f2bs(b.y); v[6] = f2bs(b.z); v[7] = f2bs(b.w);
    *reinterpret_cast<short8*>(l) = v;
}

// async global->LDS: each lane copies 16B to (wave-uniform base) + lane*16
__device__ __forceinline__ void gload_lds16(const short* g, short* l) {
    __builtin_amdgcn_global_load_lds(
        (const __attribute__((address_space(1))) void*)g,
        (__attribute__((address_space(3))) void*)l, 16, 0, 0);
}

#define LDSTR 72   // padded LDS row stride (shorts) for transposed tiles

// ---------------------------------------------------------------------------
// In-block dtype probe: every block inspects the same first 8KB of x
// (L2-hot after first touch).  fp32 data viewed via low-half<<16 produces
// huge/NaN bf16 patterns; true bf16 N(0,1) never exceeds ~6.  Deterministic
// and identical across blocks -> graph-safe, no cross-block dependency.
// Requires 256 threads.  Returns 1 = fp32, 0 = bf16.
// ---------------------------------------------------------------------------
__device__ __forceinline__ int probe_mode(const void* x) {
    const uint4* p = (const uint4*)x;
    const int tid = threadIdx.x;
    bool bad = false;
    #pragma unroll
    for (int i = 0; i < 2; ++i) {
        uint4 u = p[tid + i * 256];
        const unsigned w[4] = {u.x, u.y, u.z, u.w};
        #pragma unroll
        for (int k = 0; k < 4; ++k) {
            const float f = __uint_as_float(w[k] << 16);   // low half (even short)
            if (!(fabsf(f) <= 1e9f)) bad = true;
        }
    }
    return __syncthreads_or(bad ? 1 : 0) ? 1 : 0;
}

// ---------------------------------------------------------------------------
// Kernel 1: convert x, Wq/Wk/Wv/Wo, biases -> bf16 workspace (self-probing).
// Chunks of 8 elems: x 524288 | W 4x32768 | b 4x64 = 655616 -> 2561 blocks.
// ---------------------------------------------------------------------------
template <typename T>
__device__ __forceinline__ void convert_body(
    const void* const* in, short* xb, short* Wb, short* bb, int c)
{
    if (c < 524288) {
        stage8((const T*)in[0] + (size_t)c * 8, xb + (size_t)c * 8);
    } else if (c < 655360) {
        const int c2 = c - 524288;
        const int w = c2 >> 15;             // 0..3 : Wq Wk Wv Wo
        const int off = (c2 & 32767) * 8;
        const T* src = (const T*)in[w == 0 ? 1 : (w == 1 ? 3 : (w == 2 ? 5 : 7))];
        stage8(src + off, Wb + w * 262144 + off);
    } else if (c < 655616) {
        const int c3 = c - 655360;          // 0..255
        const int bsel = c3 >> 6;
        const int off = (c3 & 63) * 8;
        const T* src = (const T*)in[bsel == 0 ? 2 : (bsel == 1 ? 4 : (bsel == 2 ? 6 : 8))];
        stage8(src + off, bb + bsel * 512 + off);
    }
}

__global__ __launch_bounds__(256) void convert_all(
    const void* x, const void* Wq, const void* bq,
    const void* Wk, const void* bk, const void* Wv, const void* bv,
    const void* Wo, const void* bo,
    short* __restrict__ xb, short* __restrict__ Wb, short* __restrict__ bb)
{
    const void* in[9] = {x, Wq, bq, Wk, bk, Wv, bv, Wo, bo};
    const int mode = probe_mode(x);
    const int c = blockIdx.x * 256 + threadIdx.x;
    if (mode) convert_body<float>(in, xb, Wb, bb, c);
    else      convert_body<bf16>(in, xb, Wb, bb, c);
}

// ---------------------------------------------------------------------------
// Kernel 2: fused QKV projection, bf16 ws inputs, global_load_lds staging
// (validated round 6).  Grid (64,12); blockIdx.y>>2 selects Q/K/V.
// ---------------------------------------------------------------------------
__global__ __launch_bounds__(256) void qkv_gemm_dl(
    const short* __restrict__ xb, const short* __restrict__ Wb,
    const short* __restrict__ bb,
    bf16* __restrict__ Qf, bf16* __restrict__ Kf, bf16* __restrict__ Vf)
{
    const int mtile = blockIdx.x;            // 0..63
    const int ntile = blockIdx.y;            // 0..11
    const int which = ntile >> 2;
    const short* W = Wb + (size_t)which * 262144;
    const bf16* bias = (const bf16*)(bb + which * 512);
    bf16* outp = (which == 0) ? Qf : ((which == 1) ? Kf : Vf);
    const int nbase = (ntile & 3) * 128;
    const int mbase = mtile * 128;

    __shared__ short As[128 * 64];   // packed: row stride 64 shorts
    __shared__ short Bs[128 * 64];

    const int tid  = threadIdx.x;
    const int wave = tid >> 6, lane = tid & 63;
    const int wm = wave >> 1, wn = wave & 1;
    const int lm = lane & 15, quad = lane >> 4;
    const int srow = lane >> 3;           // 0..7 within issue
    const int scol = (lane & 7) * 8;      // 0,8,..,56

    floatx4 acc[4][4];
    const floatx4 zero = {0.f, 0.f, 0.f, 0.f};
    #pragma unroll
    for (int mt = 0; mt < 4; ++mt)
        #pragma unroll
        for (int nt = 0; nt < 4; ++nt) acc[mt][nt] = zero;

    for (int kt = 0; kt < EMB; kt += 64) {
        #pragma unroll
        for (int j = 0; j < 4; ++j) {
            const int issue = wave * 4 + j;          // 0..15, 8 rows each
            const int row = issue * 8 + srow;
            gload_lds16(xb + (size_t)(mbase + row) * EMB + kt + scol,
                        &As[issue * 512]);
            gload_lds16(W  + (size_t)(nbase + row) * EMB + kt + scol,
                        &Bs[issue * 512]);
        }
        __syncthreads();
        #pragma unroll
        for (int ks = 0; ks < 2; ++ks) {
            short8 af[4], bfr[4];
            #pragma unroll
            for (int mt = 0; mt < 4; ++mt)
                af[mt] = *reinterpret_cast<const short8*>(
                    &As[(wm * 64 + mt * 16 + lm) * 64 + ks * 32 + quad * 8]);
            #pragma unroll
            for (int nt = 0; nt < 4; ++nt)
                bfr[nt] = *reinterpret_cast<const short8*>(
                    &Bs[(wn * 64 + nt * 16 + lm) * 64 + ks * 32 + quad * 8]);
            #pragma unroll
            for (int mt = 0; mt < 4; ++mt)
                #pragma unroll
                for (int nt = 0; nt < 4; ++nt)
                    acc[mt][nt] = __builtin_amdgcn_mfma_f32_16x16x32_bf16(
                        af[mt], bfr[nt], acc[mt][nt], 0, 0, 0);
        }
        __syncthreads();
    }

    #pragma unroll
    for (int nt = 0; nt < 4; ++nt) {
        const int col = nbase + wn * 64 + nt * 16 + lm;   // 0..511
        const float bv_ = load_elem(bias, col & 511);
        const int h = col >> 6, d = col & 63;
        #pragma unroll
        for (int mt = 0; mt < 4; ++mt)
            #pragma unroll
            for (int r = 0; r < 4; ++r) {
                const int row = mbase + wm * 64 + mt * 16 + quad * 4 + r;
                const int b = row >> 12, t = row & (T_SEQ - 1);
                float v = acc[mt][nt][r] + bv_;
                if (which != 2) v = (v > 0.f) ? (v + 1.f) : __expf(v);  // elu+1
                outp[(((size_t)(b * NH + h)) * T_SEQ + t) * HD + d] = __float2bfloat16(v);
            }
    }
}

// ---------------------------------------------------------------------------
// Kernel 3: per-chunk (K^T V)^T via MFMA + k column sums.  1024 blocks.
// Emits S^T directly (A=V-frags, B=K-frags): KVt[dv][dk] — lets attn stage
// its B-operand with vector loads.  Stores stay coalesced (col=dk=nt*16+lm).
// ---------------------------------------------------------------------------
__global__ __launch_bounds__(256) void chunk_kv(
    const bf16* __restrict__ Kf, const bf16* __restrict__ Vf,
    float* __restrict__ KVt, float* __restrict__ ksum)
{
    const int bh = blockIdx.x >> 6;
    const int c  = blockIdx.x & 63;
    __shared__ short Kt[64 * LDSTR];   // Kt[dk][s]
    __shared__ short Vt[64 * LDSTR];   // Vt[dv][s]
    const int tid = threadIdx.x;
    const bf16* kp = Kf + ((size_t)bh * T_SEQ + c * CS) * HD;
    const bf16* vp = Vf + ((size_t)bh * T_SEQ + c * CS) * HD;

    #pragma unroll
    for (int j = 0; j < 2; ++j) {
        const int u = j * 256 + tid;
        const int e0 = u * 8;
        const int s = e0 >> 6, d0 = e0 & 63;
        short8 ku = *reinterpret_cast<const short8*>(kp + e0);
        short8 vu = *reinterpret_cast<const short8*>(vp + e0);
        #pragma unroll
        for (int i = 0; i < 8; ++i) {
            Kt[(d0 + i) * LDSTR + s] = ku[i];
            Vt[(d0 + i) * LDSTR + s] = vu[i];
        }
    }
    __syncthreads();

    const int w = tid >> 6, lane = tid & 63;
    const int lm = lane & 15, quad = lane >> 4;

    floatx4 acc[4];
    const floatx4 zero = {0.f, 0.f, 0.f, 0.f};
    #pragma unroll
    for (int nt = 0; nt < 4; ++nt) acc[nt] = zero;

    #pragma unroll
    for (int ks = 0; ks < 2; ++ks) {
        short8 av = *reinterpret_cast<const short8*>(
            &Vt[(w * 16 + lm) * LDSTR + ks * 32 + quad * 8]);   // A: rows = dv
        #pragma unroll
        for (int nt = 0; nt < 4; ++nt) {
            short8 bk = *reinterpret_cast<const short8*>(
                &Kt[(nt * 16 + lm) * LDSTR + ks * 32 + quad * 8]);  // B: cols = dk
            acc[nt] = __builtin_amdgcn_mfma_f32_16x16x32_bf16(av, bk, acc[nt], 0, 0, 0);
        }
    }

    float* kvout = KVt + ((size_t)bh * NCHUNK + c) * 4096;
    #pragma unroll
    for (int nt = 0; nt < 4; ++nt)
        #pragma unroll
        for (int r = 0; r < 4; ++r) {
            const int dv = w * 16 + quad * 4 + r;
            const int dk = nt * 16 + lm;
            kvout[dv * 64 + dk] = acc[nt][r];
        }

    if (tid < 64) {
        float s = 0.f;
        #pragma unroll 8
        for (int t = 0; t < 64; ++t) s += bs2f(Kt[tid * LDSTR + t]);
        ksum[((size_t)bh * NCHUNK + c) * 64 + tid] = s;
    }
}

// ---------------------------------------------------------------------------
// Kernel 4: exclusive prefix over chunks — element-parallel (validated r5).
// Layout-agnostic (elementwise over the 4096 state slots).
// ---------------------------------------------------------------------------
__global__ __launch_bounds__(256) void prefix_kv(
    float* __restrict__ KVt, float* __restrict__ ksum)
{
    const int bh   = blockIdx.x >> 4;
    const int part = blockIdx.x & 15;
    const int tid  = threadIdx.x;
    const int e    = part * 256 + tid;
    float* base = KVt + (size_t)bh * NCHUNK * 4096 + e;

    float s = 0.f;
    #pragma unroll
    for (int cb = 0; cb < 4; ++cb) {
        float v[16];
        #pragma unroll
        for (int i = 0; i < 16; ++i) v[i] = base[(size_t)(cb * 16 + i) * 4096];
        #pragma unroll
        for (int i = 0; i < 16; ++i) {
            const float tmp = v[i];
            base[(size_t)(cb * 16 + i) * 4096] = s;
            s += tmp;
        }
    }

    if (part == 0 && tid < 64) {
        float* zb = ksum + (size_t)bh * NCHUNK * 64 + tid;
        float z = 0.f;
        #pragma unroll
        for (int cb = 0; cb < 4; ++cb) {
            float v[16];
            #pragma unroll
            for (int i = 0; i < 16; ++i) v[i] = zb[(size_t)(cb * 16 + i) * 64];
            #pragma unroll
            for (int i = 0; i < 16; ++i) {
                const float tmp = v[i];
                zb[(size_t)(cb * 16 + i) * 64] = z;
                z += tmp;
            }
        }
    }
}

// ---------------------------------------------------------------------------
// Kernel 5: per-chunk attention, all-MFMA, registerized denominator.
// P = mask(Q K^T); den = rowsum(P)+q.z (register partials + lm-butterfly);
// O = Q S_prev^T (vector-staged) + P V.  1024 blocks (bh,c).
// ---------------------------------------------------------------------------
__global__ __launch_bounds__(256) void attn_mfma(
    const bf16* __restrict__ Qf, const bf16* __restrict__ Kf,
    const bf16* __restrict__ Vf, const float* __restrict__ KVt,
    const float* __restrict__ ksum, bf16* __restrict__ Of)
{
    const int bh = blockIdx.x >> 6;
    const int c  = blockIdx.x & 63;
    const int b  = bh >> 3, h = bh & 7;

    __shared__ short Qs [64 * LDSTR];  // Q[t][d]
    __shared__ short Ksn[64 * LDSTR];  // K[s][d]
    __shared__ short Vt [64 * LDSTR];  // V^T[dv][s]
    __shared__ short Ps [64 * LDSTR];  // masked scores P[t][s]
    __shared__ short St [64 * LDSTR];  // S_prev^T[dv][dk] (bf16)
    __shared__ float zprev[64];

    const int tid = threadIdx.x;
    const int w = tid >> 6, lane = tid & 63;
    const int lm = lane & 15, quad = lane >> 4;
    const size_t coff = ((size_t)bh * T_SEQ + c * CS) * HD;
    const float* Sp = KVt + ((size_t)bh * NCHUNK + c) * 4096;  // [dv][dk]

    #pragma unroll
    for (int j = 0; j < 2; ++j) {
        const int u  = j * 256 + tid;
        const int e0 = u * 8;
        const int r = e0 >> 6, cc = e0 & 63;
        *reinterpret_cast<short8*>(&Qs [r * LDSTR + cc]) =
            *reinterpret_cast<const short8*>(Qf + coff + e0);
        *reinterpret_cast<short8*>(&Ksn[r * LDSTR + cc]) =
            *reinterpret_cast<const short8*>(Kf + coff + e0);
        short8 vu = *reinterpret_cast<const short8*>(Vf + coff + e0);
        #pragma unroll
        for (int i = 0; i < 8; ++i) Vt[(cc + i) * LDSTR + r] = vu[i];
    }
    // S_prev^T (fp32, [dv][dk]) -> St[dv][dk] bf16: vector loads, 8B stores
    #pragma unroll
    for (int j = 0; j < 4; ++j) {
        const int u  = j * 256 + tid;          // 0..1023 float4
        const int dv = u >> 4, d0 = (u & 15) * 4;
        const float4 s4 = reinterpret_cast<const float4*>(Sp)[u];
        short4v pk;
        pk[0] = f2bs(s4.x); pk[1] = f2bs(s4.y);
        pk[2] = f2bs(s4.z); pk[3] = f2bs(s4.w);
        *reinterpret_cast<short4v*>(&St[dv * LDSTR + d0]) = pk;
    }
    if (tid < 64) zprev[tid] = ksum[((size_t)bh * NCHUNK + c) * 64 + tid];
    __syncthreads();

    const floatx4 zero = {0.f, 0.f, 0.f, 0.f};
    // A-fragments of Q (rows t = w*16 + quad*4 + r), shared by QK^T and Q@S
    short8 aq[2];
    #pragma unroll
    for (int ks = 0; ks < 2; ++ks)
        aq[ks] = *reinterpret_cast<const short8*>(
            &Qs[(w * 16 + lm) * LDSTR + ks * 32 + quad * 8]);

    // ---- P = Q K^T ----
    floatx4 pacc[4];
    #pragma unroll
    for (int nt = 0; nt < 4; ++nt) pacc[nt] = zero;
    #pragma unroll
    for (int ks = 0; ks < 2; ++ks)
        #pragma unroll
        for (int nt = 0; nt < 4; ++nt) {
            short8 bk = *reinterpret_cast<const short8*>(
                &Ksn[(nt * 16 + lm) * LDSTR + ks * 32 + quad * 8]);
            pacc[nt] = __builtin_amdgcn_mfma_f32_16x16x32_bf16(aq[ks], bk, pacc[nt], 0, 0, 0);
        }

    // mask + write Ps; accumulate per-row sums in registers
    float tot[4] = {0.f, 0.f, 0.f, 0.f};
    #pragma unroll
    for (int nt = 0; nt < 4; ++nt)
        #pragma unroll
        for (int r = 0; r < 4; ++r) {
            const int t = w * 16 + quad * 4 + r;
            const int s = nt * 16 + lm;
            const float m = (s <= t) ? pacc[nt][r] : 0.f;
            Ps[t * LDSTR + s] = f2bs(m);
            tot[r] += m;
        }
    // + q.z partials: lane lm covers d = lm, lm+16, lm+32, lm+48
    #pragma unroll
    for (int r = 0; r < 4; ++r) {
        const int t = w * 16 + quad * 4 + r;
        #pragma unroll
        for (int j = 0; j < 4; ++j) {
            const int d = lm + j * 16;
            tot[r] += bs2f(Qs[t * LDSTR + d]) * zprev[d];
        }
    }
    // butterfly over the 16 lm-lanes (xor bits 0..3 stay within quad-group)
    #pragma unroll
    for (int mask = 1; mask < 16; mask <<= 1)
        #pragma unroll
        for (int r = 0; r < 4; ++r) tot[r] += __shfl_xor(tot[r], mask);
    float rdenl[4];
    #pragma unroll
    for (int r = 0; r < 4; ++r) rdenl[r] = 1.f / (tot[r] + 1e-6f);

    // ---- O = Q @ S_prev^T (MFMA) ----
    floatx4 oacc[4];
    #pragma unroll
    for (int nt = 0; nt < 4; ++nt) oacc[nt] = zero;
    #pragma unroll
    for (int ks = 0; ks < 2; ++ks)
        #pragma unroll
        for (int nt = 0; nt < 4; ++nt) {
            short8 bs = *reinterpret_cast<const short8*>(
                &St[(nt * 16 + lm) * LDSTR + ks * 32 + quad * 8]);
            oacc[nt] = __builtin_amdgcn_mfma_f32_16x16x32_bf16(aq[ks], bs, oacc[nt], 0, 0, 0);
        }
    __syncthreads();   // Ps complete

    // ---- O += P V ----
    #pragma unroll
    for (int ks = 0; ks < 2; ++ks) {
        short8 ap = *reinterpret_cast<const short8*>(
            &Ps[(w * 16 + lm) * LDSTR + ks * 32 + quad * 8]);
        #pragma unroll
        for (int nt = 0; nt < 4; ++nt) {
            short8 bv = *reinterpret_cast<const short8*>(
                &Vt[(nt * 16 + lm) * LDSTR + ks * 32 + quad * 8]);
            oacc[nt] = __builtin_amdgcn_mfma_f32_16x16x32_bf16(ap, bv, oacc[nt], 0, 0, 0);
        }
    }

    #pragma unroll
    for (int nt = 0; nt < 4; ++nt)
        #pragma unroll
        for (int r = 0; r < 4; ++r) {
            const int t  = w * 16 + quad * 4 + r;
            const int dv = nt * 16 + lm;
            const int tg = c * CS + t;
            Of[((size_t)(b * T_SEQ + tg)) * EMB + h * HD + dv] =
                __float2bfloat16(oacc[nt][r] * rdenl[r]);
        }
}

// ---------------------------------------------------------------------------
// Kernel 6: output projection, self-probing store dtype.  out = Of @ Wo^T + bo.
// Grid (64, 4).
// ---------------------------------------------------------------------------
__global__ __launch_bounds__(256) void out_proj_dl(
    const void* __restrict__ xprobe,
    const short* __restrict__ A, const short* __restrict__ Wb,
    const short* __restrict__ bb, void* __restrict__ out)
{
    const int mode = probe_mode(xprobe);

    const int mbase = blockIdx.x * 128;
    const int nbase = blockIdx.y * 128;
    const short* W = Wb + (size_t)3 * 262144;
    const bf16* bias = (const bf16*)(bb + 3 * 512);

    __shared__ short As[128 * 64];
    __shared__ short Bs[128 * 64];

    const int tid  = threadIdx.x;
    const int wave = tid >> 6, lane = tid & 63;
    const int wm = wave >> 1, wn = wave & 1;
    const int lm = lane & 15, quad = lane >> 4;
    const int srow = lane >> 3;
    const int scol = (lane & 7) * 8;

    floatx4 acc[4][4];
    const floatx4 zero = {0.f, 0.f, 0.f, 0.f};
    #pragma unroll
    for (int mt = 0; mt < 4; ++mt)
        #pragma unroll
        for (int nt = 0; nt < 4; ++nt) acc[mt][nt] = zero;

    for (int kt = 0; kt < EMB; kt += 64) {
        #pragma unroll
        for (int j = 0; j < 4; ++j) {
            const int issue = wave * 4 + j;
            const int row = issue * 8 + srow;
            gload_lds16(A + (size_t)(mbase + row) * EMB + kt + scol,
                        &As[issue * 512]);
            gload_lds16(W + (size_t)(nbase + row) * EMB + kt + scol,
                        &Bs[issue * 512]);
        }
        __syncthreads();
        #pragma unroll
        for (int ks = 0; ks < 2; ++ks) {
            short8 af[4], bfr[4];
            #pragma unroll
            for (int mt = 0; mt < 4; ++mt)
                af[mt] = *reinterpret_cast<const short8*>(
                    &As[(wm * 64 + mt * 16 + lm) * 64 + ks * 32 + quad * 8]);
            #pragma unroll
            for (int nt = 0; nt < 4; ++nt)
                bfr[nt] = *reinterpret_cast<const short8*>(
                    &Bs[(wn * 64 + nt * 16 + lm) * 64 + ks * 32 + quad * 8]);
            #pragma unroll
            for (int mt = 0; mt < 4; ++mt)
                #pragma unroll
                for (int nt = 0; nt < 4; ++nt)
                    acc[mt][nt] = __builtin_amdgcn_mfma_f32_16x16x32_bf16(
                        af[mt], bfr[nt], acc[mt][nt], 0, 0, 0);
        }
        __syncthreads();
    }

    #pragma unroll
    for (int nt = 0; nt < 4; ++nt) {
        const int col = nbase + wn * 64 + nt * 16 + lm;
        const float bv_ = load_elem(bias, col);
        #pragma unroll
        for (int mt = 0; mt < 4; ++mt)
            #pragma unroll
            for (int r = 0; r < 4; ++r) {
                const int row = mbase + wm * 64 + mt * 16 + quad * 4 + r;
                const float v = acc[mt][nt][r] + bv_;
                if (mode) ((float*)out)[(size_t)row * EMB + col] = v;
                else      ((bf16*)out)[(size_t)row * EMB + col] = __float2bfloat16(v);
            }
    }
}

// ---------------------------------------------------------------------------
extern "C" void kernel_launch(void* const* d_in, const int* in_sizes, int n_in,
                              void* d_out, int out_size, void* d_ws, size_t ws_size,
                              hipStream_t stream)
{
    // workspace (~50.3 MB of the 256 MB ws):
    //   reserved 64 B
    //   Qf/Kf/Vf : bf16 4,194,304 each                (24 MB)
    //   union  : [ KVt fp32 4,194,304 | xb bf16 4,194,304 ]  (16 MB)
    //   ksum   : fp32 65,536                           (0.25 MB)
    //   Of     : bf16 4,194,304                        (8 MB)
    //   Wb     : bf16 4x262,144                        (2 MB)
    //   bb     : bf16 4x512                            (4 KB)
    bf16* Qf = (bf16*)((char*)d_ws + 64);
    bf16* Kf = Qf + 4194304;
    bf16* Vf = Kf + 4194304;
    float* KVt = (float*)(Vf + 4194304);
    short* xb = (short*)KVt;                // aliased (disjoint lifetime)
    float* ks = KVt + 4194304;
    bf16* Of = (bf16*)(ks + 65536);
    short* Wb = (short*)(Of + 4194304);
    short* bb = Wb + 1048576;

    convert_all<<<dim3(2561), 256, 0, stream>>>(
        d_in[0], d_in[1], d_in[2], d_in[3], d_in[4],
        d_in[5], d_in[6], d_in[7], d_in[8], xb, Wb, bb);

    qkv_gemm_dl<<<dim3(64, 12), 256, 0, stream>>>(xb, Wb, bb, Qf, Kf, Vf);
    chunk_kv<<<dim3(BHEADS * NCHUNK), 256, 0, stream>>>(Kf, Vf, KVt, ks);
    prefix_kv<<<dim3(BHEADS * 16), 256, 0, stream>>>(KVt, ks);
    attn_mfma<<<dim3(BHEADS * NCHUNK), 256, 0, stream>>>(Qf, Kf, Vf, KVt, ks, Of);

    out_proj_dl<<<dim3(64, 4), 256, 0, stream>>>(
        d_in[0], (const short*)Of, Wb, bb, d_out);
}